// Round 8
// baseline (290.903 us; speedup 1.0000x reference)
//
#include <hip/hip_runtime.h>
#include <cstdint>

#define TAU_INV 5.0f
#define L2E 1.4426950408889634f

using ushort = unsigned short;
typedef __attribute__((ext_vector_type(8))) short s16x8;
typedef __attribute__((ext_vector_type(4))) float f32x4;

static __device__ __forceinline__ ushort f2bf(float x) {
  unsigned u = __float_as_uint(x);
  return (ushort)((u + 0x7fffu + ((u >> 16) & 1u)) >> 16);
}

static __device__ __forceinline__ float fexp2(float x) {
#if __has_builtin(__builtin_amdgcn_exp2f)
  return __builtin_amdgcn_exp2f(x);
#else
  return exp2f(x);
#endif
}

static __device__ __forceinline__ void gload_lds16(const void* g, void* l) {
  __builtin_amdgcn_global_load_lds(
      reinterpret_cast<const __attribute__((address_space(1))) void*>(
          reinterpret_cast<uintptr_t>(g)),
      reinterpret_cast<__attribute__((address_space(3))) void*>(
          (unsigned)reinterpret_cast<uintptr_t>(l)),
      16, 0, 0);
}

// bijective XCD-chunked swizzle of the (y*gx+x) tile space (m204 formula)
static __device__ __forceinline__ void xcd_swizzle(int gx, int gy, int& bx, int& by) {
  int nwg = gx * gy;
  int flat = by * gx + bx;
  int q = nwg >> 3, r = nwg & 7;
  int xcd = flat & 7, sl = flat >> 3;
  int tile = (xcd < r ? xcd * (q + 1) : r * (q + 1) + (xcd - r) * q) + sl;
  by = tile / gx;
  bx = tile - by * gx;
}

// ---------------- fused f32->bf16 convert + partial channel pool ----------------
__global__ void k_cvt_pool(const float* __restrict__ feat, ushort* __restrict__ obf,
                           float* __restrict__ gpart) {
  int b = blockIdx.y, pc = blockIdx.x, t = threadIdx.x;
  const float* fp = feat + ((size_t)b * 784 + (size_t)pc * 7) * 1024;
  ushort* op = obf + ((size_t)b * 784 + (size_t)pc * 7) * 1024;
  float4 acc = {0.f, 0.f, 0.f, 0.f};
#pragma unroll
  for (int p = 0; p < 7; ++p) {
    float4 v = ((const float4*)(fp + (size_t)p * 1024))[t];
    acc.x += v.x; acc.y += v.y; acc.z += v.z; acc.w += v.w;
    ushort4 r;
    r.x = f2bf(v.x); r.y = f2bf(v.y); r.z = f2bf(v.z); r.w = f2bf(v.w);
    ((ushort4*)(op + (size_t)p * 1024))[t] = r;
  }
  ((float4*)(gpart + ((size_t)b * 112 + pc) * 1024))[t] = acc;
}

__global__ void k_gpool_fin(const float* __restrict__ gpart, float* __restrict__ g) {
  int idx = blockIdx.x * 256 + threadIdx.x;
  int b = idx >> 10, c = idx & 1023;
  float s = 0.f;
#pragma unroll 4
  for (int pc = 0; pc < 112; ++pc) s += gpart[((size_t)b * 112 + pc) * 1024 + c];
  g[idx] = s * (1.0f / 784.0f);
}

__global__ void k_dense1_part(const float* __restrict__ g, const float* __restrict__ W,
                              float* __restrict__ part1) {
  int d = blockIdx.x * 256 + threadIdx.x;
  int k0 = blockIdx.y * 64;
  __shared__ float gs[512];
  for (int i = threadIdx.x; i < 512; i += 256) gs[i] = g[(i >> 6) * 1024 + k0 + (i & 63)];
  __syncthreads();
  float acc[8] = {};
  for (int kk = 0; kk < 64; ++kk) {
    float w = W[(size_t)(k0 + kk) * 2048 + d];
#pragma unroll
    for (int b = 0; b < 8; ++b) acc[b] += gs[b * 64 + kk] * w;
  }
#pragma unroll
  for (int b = 0; b < 8; ++b) part1[((size_t)blockIdx.y * 8 + b) * 2048 + d] = acc[b];
}

__global__ void k_dense1_fin(const float* __restrict__ part1, const float* __restrict__ bias,
                             float* __restrict__ h) {
  int idx = blockIdx.x * 256 + threadIdx.x;
  int b = idx >> 11, d = idx & 2047;
  float s = bias[d];
#pragma unroll
  for (int ks = 0; ks < 16; ++ks) s += part1[((size_t)ks * 8 + b) * 2048 + d];
  h[idx] = fmaxf(s, 0.f);
}

__global__ void k_dense2_part(const float* __restrict__ h, const float* __restrict__ W2,
                              float* __restrict__ part2) {
  int d = threadIdx.x;
  int k0 = blockIdx.x * 64;
  __shared__ float hs[512];
  for (int i = threadIdx.x; i < 512; i += 128) hs[i] = h[(i >> 6) * 2048 + k0 + (i & 63)];
  __syncthreads();
  float acc[8] = {};
  for (int kk = 0; kk < 64; ++kk) {
    float w = W2[(size_t)(k0 + kk) * 128 + d];
#pragma unroll
    for (int b = 0; b < 8; ++b) acc[b] += hs[b * 64 + kk] * w;
  }
#pragma unroll
  for (int b = 0; b < 8; ++b) part2[((size_t)blockIdx.x * 8 + b) * 128 + d] = acc[b];
}

__global__ void k_head_fin(const float* __restrict__ p2q, const float* __restrict__ p2k,
                           const float* __restrict__ bq, const float* __restrict__ bk,
                           float* __restrict__ qg, float* __restrict__ kg,
                           float* __restrict__ lpos) {
  int b = blockIdx.x, lane = threadIdx.x;
  float q0 = bq[lane], q1 = bq[lane + 64];
  float k0 = bk[lane], k1 = bk[lane + 64];
#pragma unroll
  for (int s = 0; s < 32; ++s) {
    size_t base = ((size_t)s * 8 + b) * 128;
    q0 += p2q[base + lane]; q1 += p2q[base + lane + 64];
    k0 += p2k[base + lane]; k1 += p2k[base + lane + 64];
  }
  float sq = q0 * q0 + q1 * q1, sk = k0 * k0 + k1 * k1;
#pragma unroll
  for (int d = 1; d < 64; d <<= 1) { sq += __shfl_xor(sq, d); sk += __shfl_xor(sk, d); }
  float rq = 1.0f / sqrtf(fmaxf(sq, 1e-12f));
  float rk = 1.0f / sqrtf(fmaxf(sk, 1e-12f));
  q0 *= rq; q1 *= rq; k0 *= rk; k1 *= rk;
  qg[b * 128 + lane] = q0; qg[b * 128 + 64 + lane] = q1;
  kg[b * 128 + lane] = k0; kg[b * 128 + 64 + lane] = k1;
  float lp = q0 * k0 + q1 * k1;
#pragma unroll
  for (int d = 1; d < 64; d <<= 1) lp += __shfl_xor(lp, d);
  if (lane == 0) lpos[b] = lp;
}

// ---------------- transpose + convert ----------------
__global__ void k_transpose_cvt(const float* __restrict__ W, ushort* __restrict__ Wt, int K, int N) {
  __shared__ float tile[32][33];
  int n0 = blockIdx.x * 32, k0 = blockIdx.y * 32;
  int tx = threadIdx.x & 31, ty = threadIdx.x >> 5;
#pragma unroll
  for (int i = 0; i < 32; i += 8)
    tile[ty + i][tx] = W[(size_t)(k0 + ty + i) * N + n0 + tx];
  __syncthreads();
#pragma unroll
  for (int i = 0; i < 32; i += 8)
    Wt[(size_t)(n0 + ty + i) * K + k0 + tx] = f2bf(tile[tx][ty + i]);
}

// ============ 256x256 8-wave GEMM (E1), counted-vmcnt pipeline (T3+T4+T5) ============
// 2-deep prefetch; per-tile: {compute cur} -> lgkm0+barrier -> issue(t+2 into cur)
// -> vmcnt(8) -> barrier. Never drains vmcnt to 0 in steady state.
__global__ __launch_bounds__(512, 2) void k_gemm256(
    const ushort* __restrict__ A, const ushort* __restrict__ B,
    const float* __restrict__ bias, ushort* __restrict__ O,
    int Mvalid, int K, int ldOut) {
  extern __shared__ unsigned char smem[];
  const int tid = threadIdx.x;
  int bx = blockIdx.x, by = blockIdx.y;
  xcd_swizzle(gridDim.x, gridDim.y, bx, by);
  const int mBase = by * 256, nBase = bx * 256;
  const int lane = tid & 63;
  const int wid_u = __builtin_amdgcn_readfirstlane(tid >> 6);
  const int wm = wid_u >> 2, wn = wid_u & 3;       // 2M x 4N waves
  const int lg = lane >> 4, li = lane & 15;
  const int lrow = lane >> 3, lchunk = lane & 7;
  const int gc = (lchunk ^ lrow) << 3;             // swizzled source chunk (elements)
  const int qb = wm * 2 + (wn & 1);                // B-quarter this wave stages
  const int hB = wn >> 1;                          // B-half this wave reads/stages

  const ushort* aSrc[4]; const ushort* bSrc[4];
  unsigned aDst[4], bDst[4];
#pragma unroll
  for (int j = 0; j < 4; ++j) {
    int r2a = wn * 32 + j * 8 + lrow;
    int ga = mBase + wm * 128 + r2a; ga = ga < Mvalid ? ga : Mvalid - 1;
    aSrc[j] = A + (size_t)ga * K + gc;
    aDst[j] = (unsigned)(wm * 16384 + (wn * 32 + j * 8) * 128);
    int r2b = qb * 32 + j * 8 + lrow;
    int gb = nBase + hB * 128 + r2b;
    bSrc[j] = B + (size_t)gb * K + gc;
    bDst[j] = (unsigned)(32768 + hB * 16384 + (qb * 32 + j * 8) * 128);
  }

  f32x4 acc[8][4] = {};
  const int nt = K >> 6;

  auto ISSUE = [&](unsigned base, int ko) {
#pragma unroll
    for (int j = 0; j < 4; ++j) gload_lds16(aSrc[j] + ko, smem + base + aDst[j]);
#pragma unroll
    for (int j = 0; j < 4; ++j) gload_lds16(bSrc[j] + ko, smem + base + bDst[j]);
  };

  // prologue: tiles 0 and 1 in flight; wait only for tile 0 (8 newest stay outstanding)
  ISSUE(0u, 0);
  if (nt > 1) {
    ISSUE(65536u, 64);
    asm volatile("s_waitcnt vmcnt(8)" ::: "memory");
  } else {
    asm volatile("s_waitcnt vmcnt(0)" ::: "memory");
  }
  __builtin_amdgcn_s_barrier();
  __builtin_amdgcn_sched_barrier(0);

  for (int t = 0; t < nt; ++t) {
    const unsigned bb = (unsigned)(t & 1) * 65536u;
    const unsigned char* Ah = smem + bb + wm * 16384;
    const unsigned char* Bh = smem + bb + 32768 + hB * 16384;

    s16x8 bf[4][2];
#pragma unroll
    for (int ni = 0; ni < 4; ++ni) {
      int r2 = (wn & 1) * 64 + ni * 16 + li;
#pragma unroll
      for (int ks = 0; ks < 2; ++ks)
        bf[ni][ks] = *(const s16x8*)(const void*)(Bh + r2 * 128 + (((ks * 4 + lg) ^ (r2 & 7)) << 4));
    }
#pragma unroll
    for (int mp = 0; mp < 4; ++mp) {   // 4 clusters of 2 mi each
      s16x8 af[2][2];
#pragma unroll
      for (int e = 0; e < 2; ++e) {
        int r2 = (mp * 2 + e) * 16 + li;
#pragma unroll
        for (int ks = 0; ks < 2; ++ks)
          af[e][ks] = *(const s16x8*)(const void*)(Ah + r2 * 128 + (((ks * 4 + lg) ^ (r2 & 7)) << 4));
      }
      __builtin_amdgcn_s_setprio(1);
#pragma unroll
      for (int e = 0; e < 2; ++e)
#pragma unroll
        for (int ni = 0; ni < 4; ++ni)
#pragma unroll
          for (int ks = 0; ks < 2; ++ks)
            acc[mp * 2 + e][ni] =
                __builtin_amdgcn_mfma_f32_16x16x32_bf16(af[e][ks], bf[ni][ks], acc[mp * 2 + e][ni], 0, 0, 0);
      __builtin_amdgcn_s_setprio(0);
    }

    // tile end: readers done -> reuse cur for t+2 -> counted wait for t+1
    __builtin_amdgcn_sched_barrier(0);
    asm volatile("s_waitcnt lgkmcnt(0)" ::: "memory");
    __builtin_amdgcn_s_barrier();          // all waves finished reading buffer bb
    if (t + 2 < nt) {
      ISSUE(bb, (t + 2) << 6);
      asm volatile("s_waitcnt vmcnt(8)" ::: "memory");   // t+1 staged; t+2 in flight
    } else if (t + 1 < nt) {
      asm volatile("s_waitcnt vmcnt(0)" ::: "memory");   // last tile: drain
    }
    __builtin_amdgcn_s_barrier();          // next buffer visible to all waves
    __builtin_amdgcn_sched_barrier(0);
  }

  // epilogue: bias + relu + bf16 store (N always full here)
#pragma unroll
  for (int ni = 0; ni < 4; ++ni) {
    int c = nBase + wn * 64 + ni * 16 + li;
    float bv = bias[c];
#pragma unroll
    for (int mi = 0; mi < 8; ++mi) {
#pragma unroll
      for (int rg = 0; rg < 4; ++rg) {
        int r = mBase + wm * 128 + mi * 16 + lg * 4 + rg;
        if (r < Mvalid) {
          float v = fmaxf(acc[mi][ni][rg] + bv, 0.f);
          O[(size_t)r * ldOut + c] = f2bf(v);
        }
      }
    }
  }
}

// ---------------- MFMA GEMM: 128x128 tile, BK=64, double-buffered 2-phase ----------------
template <int EPI>
__global__ __launch_bounds__(256) void k_gemm_abt(
    const ushort* __restrict__ A, const ushort* __restrict__ B,
    const float* __restrict__ bias, void* __restrict__ o0, void* __restrict__ o1,
    int Mvalid, int Nvalid, int Kloop, int lda, int ldb, int ldOut, int ntiles,
    float scale, long sA, long sB) {
  __shared__ unsigned char smem[65536];
  const int tid = threadIdx.x;
  int bx = blockIdx.x, by = blockIdx.y;
  const int bz = blockIdx.z;
  xcd_swizzle(gridDim.x, gridDim.y, bx, by);
  const ushort* Ab = A + (size_t)bz * sA;
  const ushort* Bb = B + (size_t)bz * sB;
  const int mBase = by * 128, nBase = bx * 128;
  const int lane = tid & 63;
  const int wid = tid >> 6;
  const int wid_u = __builtin_amdgcn_readfirstlane(wid);
  const int wm = wid >> 1, wn = wid & 1;
  const int lg = lane >> 4, li = lane & 15;
  const int lrow = lane >> 3, lchunk = lane & 7;

  const ushort* aSrc[4];
  const ushort* bSrc[4];
  int ldsOff[4];
#pragma unroll
  for (int j = 0; j < 4; ++j) {
    int r = wid_u * 32 + j * 8 + lrow;
    int gc = (lchunk ^ lrow) << 3;
    int ga = mBase + r; ga = ga < Mvalid ? ga : Mvalid - 1;
    int gb = nBase + r; gb = gb < Nvalid ? gb : Nvalid - 1;
    aSrc[j] = Ab + (size_t)ga * lda + gc;
    bSrc[j] = Bb + (size_t)gb * ldb + gc;
    ldsOff[j] = (wid_u * 32 + j * 8) * 128;
  }
  f32x4 acc[4][4] = {};

  auto STAGE = [&](int buf, int k0) {
    unsigned base = (unsigned)buf * 32768u;
#pragma unroll
    for (int j = 0; j < 4; ++j) {
      gload_lds16(aSrc[j] + k0, smem + base + ldsOff[j]);
      gload_lds16(bSrc[j] + k0, smem + base + 16384 + ldsOff[j]);
    }
  };

  const int nt = Kloop >> 6;
  STAGE(0, 0);
  __syncthreads();
  for (int t = 0; t < nt; ++t) {
    if (t + 1 < nt) STAGE((t + 1) & 1, (t + 1) << 6);
    const unsigned char* As = smem + (t & 1) * 32768;
    const unsigned char* Bs = As + 16384;
#pragma unroll
    for (int ks = 0; ks < 2; ++ks) {
      s16x8 af[4], bfr[4];
#pragma unroll
      for (int mi = 0; mi < 4; ++mi) {
        int r = wm * 64 + mi * 16 + li;
        af[mi] = *(const s16x8*)(const void*)(As + r * 128 + ((ks * 64 + lg * 16) ^ ((r & 7) << 4)));
      }
#pragma unroll
      for (int ni = 0; ni < 4; ++ni) {
        int c = wn * 64 + ni * 16 + li;
        bfr[ni] = *(const s16x8*)(const void*)(Bs + c * 128 + ((ks * 64 + lg * 16) ^ ((c & 7) << 4)));
      }
#pragma unroll
      for (int mi = 0; mi < 4; ++mi)
#pragma unroll
        for (int ni = 0; ni < 4; ++ni)
          acc[mi][ni] = __builtin_amdgcn_mfma_f32_16x16x32_bf16(af[mi], bfr[ni], acc[mi][ni], 0, 0, 0);
    }
    __syncthreads();
  }

  if constexpr (EPI == 0 || EPI == 4) {
    bool full = (mBase + 128 <= Mvalid) && (nBase + 128 <= Nvalid);
    if (full) {
#pragma unroll
      for (int ni = 0; ni < 4; ++ni) {
        int c = nBase + wn * 64 + ni * 16 + li;
        float bv = (EPI == 0) ? bias[c] : 0.f;
#pragma unroll
        for (int mi = 0; mi < 4; ++mi) {
#pragma unroll
          for (int rg = 0; rg < 4; ++rg) {
            int r = mBase + wm * 64 + mi * 16 + lg * 4 + rg;
            if constexpr (EPI == 0) {
              float v = fmaxf(acc[mi][ni][rg] + bv, 0.f);
              ((ushort*)o0)[(size_t)r * ldOut + c] = f2bf(v);
            } else {
              ((float*)o0)[(size_t)bz * ntiles + (size_t)r * ldOut + c] = acc[mi][ni][rg];
            }
          }
        }
      }
    } else {
#pragma unroll
      for (int mi = 0; mi < 4; ++mi)
#pragma unroll
        for (int ni = 0; ni < 4; ++ni) {
          int c = nBase + wn * 64 + ni * 16 + li;
#pragma unroll
          for (int rg = 0; rg < 4; ++rg) {
            int r = mBase + wm * 64 + mi * 16 + lg * 4 + rg;
            if (r < Mvalid && c < Nvalid) {
              if constexpr (EPI == 0) {
                float v = fmaxf(acc[mi][ni][rg] + bias[c], 0.f);
                ((ushort*)o0)[(size_t)r * ldOut + c] = f2bf(v);
              } else {
                ((float*)o0)[(size_t)bz * ntiles + (size_t)r * ldOut + c] = acc[mi][ni][rg];
              }
            }
          }
        }
    }
  } else if constexpr (EPI == 2) {
    __syncthreads();
    float* reds = (float*)(void*)smem;   // [128][2]
#pragma unroll
    for (int mi = 0; mi < 4; ++mi)
#pragma unroll
      for (int rg = 0; rg < 4; ++rg) {
        float s = fexp2(acc[mi][0][rg] * scale) + fexp2(acc[mi][1][rg] * scale) +
                  fexp2(acc[mi][2][rg] * scale) + fexp2(acc[mi][3][rg] * scale);
#pragma unroll
        for (int d = 1; d < 16; d <<= 1) s += __shfl_xor(s, d);
        int rl = wm * 64 + mi * 16 + lg * 4 + rg;
        if (li == 0) reds[rl * 2 + wn] = s;
      }
    __syncthreads();
    if (tid < 128) {
      size_t idx = (size_t)(mBase + tid) * ntiles + bx;
      ((float*)o0)[idx] = reds[tid * 2] + reds[tid * 2 + 1];
    }
  } else if constexpr (EPI == 3) {
    __syncthreads();
    float* redv = (float*)(void*)smem;
    int* redi = (int*)(void*)(smem + 1024);
#pragma unroll
    for (int mi = 0; mi < 4; ++mi)
#pragma unroll
      for (int rg = 0; rg < 4; ++rg) {
        float bv = -3.4e38f;
        int bi = 0x7fffffff;
#pragma unroll
        for (int ni = 0; ni < 4; ++ni) {
          int c = nBase + wn * 64 + ni * 16 + li;
          float v = (c < Nvalid) ? acc[mi][ni][rg] : -3.4e38f;
          if (v > bv || (v == bv && c < bi)) { bv = v; bi = c; }
        }
#pragma unroll
        for (int d = 1; d < 16; d <<= 1) {
          float ov = __shfl_xor(bv, d);
          int oi = __shfl_xor(bi, d);
          if (ov > bv || (ov == bv && oi < bi)) { bv = ov; bi = oi; }
        }
        int rl = wm * 64 + mi * 16 + lg * 4 + rg;
        if (li == 0) { redv[rl * 2 + wn] = bv; redi[rl * 2 + wn] = bi; }
      }
    __syncthreads();
    if (tid < 128) {
      int r = mBase + tid;
      if (r < Mvalid) {
        float v0 = redv[tid * 2], v1 = redv[tid * 2 + 1];
        int i0 = redi[tid * 2], i1 = redi[tid * 2 + 1];
        float v = v0; int bi2 = i0;
        if (v1 > v || (v1 == v && i1 < bi2)) { v = v1; bi2 = i1; }
        size_t idx = (size_t)(bz * Mvalid + r) * ntiles + bx;
        ((float*)o0)[idx] = v;
        ((int*)o1)[idx] = bi2;
      }
    }
  }
}

// ---------------- sum 4 K-slice partials + bias, l2-normalize ----------------
__global__ void k_l2n_rows(const float* __restrict__ part, const float* __restrict__ bias,
                           float* __restrict__ of, ushort* __restrict__ ob, int rows) {
  int row = blockIdx.x * 4 + (threadIdx.x >> 6);
  int lane = threadIdx.x & 63;
  if (row >= rows) return;
  size_t i0 = (size_t)row * 128 + lane;
  const size_t SL = 802816;
  float v0 = bias[lane]      + part[i0]      + part[SL + i0]      + part[2 * SL + i0]      + part[3 * SL + i0];
  float v1 = bias[lane + 64] + part[i0 + 64] + part[SL + i0 + 64] + part[2 * SL + i0 + 64] + part[3 * SL + i0 + 64];
  float ss = v0 * v0 + v1 * v1;
#pragma unroll
  for (int d = 1; d < 64; d <<= 1) ss += __shfl_xor(ss, d);
  float r = 1.0f / sqrtf(fmaxf(ss, 1e-12f));
  of[i0] = v0 * r;
  of[i0 + 64] = v1 * r;
  ob[i0] = f2bf(v0 * r);
  ob[i0 + 64] = f2bf(v1 * r);
}

// ---------------- argmax finalize + gather ----------------
__global__ void k_argmax_gather(const float* __restrict__ pval, const int* __restrict__ pidx,
                                const ushort* __restrict__ kd_bf, ushort* __restrict__ matched_bf,
                                int* __restrict__ idxf) {
  int n = blockIdx.x;
  int b = n / 784;
  float bv = pval[(size_t)n * 7];
  int bi = pidx[(size_t)n * 7];
#pragma unroll
  for (int t = 1; t < 7; ++t) {
    float v = pval[(size_t)n * 7 + t];
    int i2 = pidx[(size_t)n * 7 + t];
    if (v > bv) { bv = v; bi = i2; }
  }
  int lane = threadIdx.x;
  if (lane == 0) idxf[n] = bi;
  const ushort* src = kd_bf + (size_t)(b * 784 + bi) * 128;
  ushort* dst = matched_bf + (size_t)n * 128;
  dst[lane] = src[lane];
  dst[lane + 64] = src[lane + 64];
}

// ---------------- queue InfoNCE partials (max-free) ----------------
__global__ __launch_bounds__(256) void k_queue_nce(const float* __restrict__ queue,
                                                   const float* __restrict__ qg,
                                                   float* __restrict__ ps) {
  __shared__ float qs[1024];
  int tid = threadIdx.x;
  for (int i = tid; i < 1024; i += 256) qs[i] = qg[i];
  __syncthreads();
  int r = blockIdx.x * 256 + tid;
  const float* qr = queue + (size_t)r * 128;
  float a[8] = {0, 0, 0, 0, 0, 0, 0, 0};
  for (int j = 0; j < 128; j += 4) {
    float4 v = *(const float4*)(const void*)(qr + j);
#pragma unroll
    for (int b = 0; b < 8; ++b)
      a[b] += v.x * qs[b * 128 + j] + v.y * qs[b * 128 + j + 1] +
              v.z * qs[b * 128 + j + 2] + v.w * qs[b * 128 + j + 3];
  }
  __shared__ float lssum[8][4];
  int lane = tid & 63, w = tid >> 6;
#pragma unroll
  for (int b = 0; b < 8; ++b) {
    float s = fexp2(a[b] * (TAU_INV * L2E));
#pragma unroll
    for (int d = 1; d < 64; d <<= 1) s += __shfl_xor(s, d);
    if (lane == 0) lssum[b][w] = s;
  }
  __syncthreads();
  if (tid < 8) {
    int b = tid;
    ps[blockIdx.x * 8 + b] = lssum[b][0] + lssum[b][1] + lssum[b][2] + lssum[b][3];
  }
}

// ---------------- per-row: sum 49 partials -> log + pos dot ----------------
__global__ void k_row_lse(const float* __restrict__ psum, const int* __restrict__ idxf,
                          const float* __restrict__ qd, const float* __restrict__ kd,
                          float* __restrict__ diff) {
  int n = blockIdx.x * 4 + (threadIdx.x >> 6);
  int lane = threadIdx.x & 63;
  float s = (lane < 49) ? psum[(size_t)n * 49 + lane] : 0.f;
#pragma unroll
  for (int d = 1; d < 64; d <<= 1) s += __shfl_xor(s, d);
  int b = n / 784;
  int mr = b * 784 + idxf[n];
  float pos = qd[(size_t)n * 128 + lane] * kd[(size_t)mr * 128 + lane] +
              qd[(size_t)n * 128 + 64 + lane] * kd[(size_t)mr * 128 + 64 + lane];
#pragma unroll
  for (int d = 1; d < 64; d <<= 1) pos += __shfl_xor(pos, d);
  if (lane == 0) diff[n] = logf(s) - pos * TAU_INV;
}

// ---------------- final combine (max-free) ----------------
__global__ void k_final(const float* __restrict__ ps, const float* __restrict__ lpos,
                        const float* __restrict__ diff, float* __restrict__ out) {
  int tid = threadIdx.x;
  int lane = tid & 63, w = tid >> 6;
  __shared__ float sm[4];
  float lg = 0.f;
  for (int b = 0; b < 8; ++b) {
    float s = ps[tid * 8 + b];
#pragma unroll
    for (int d = 1; d < 64; d <<= 1) s += __shfl_xor(s, d);
    if (lane == 0) sm[w] = s;
    __syncthreads();
    if (tid == 0) {
      float S = sm[0] + sm[1] + sm[2] + sm[3];
      float lp = lpos[b] * TAU_INV;
      S += fexp2(lp * L2E);
      lg += logf(S) - lp;
    }
    __syncthreads();
  }
  float v = 0.f;
  for (int i = tid; i < 6272; i += 256) v += diff[i];
#pragma unroll
  for (int d = 1; d < 64; d <<= 1) v += __shfl_xor(v, d);
  if (lane == 0) sm[w] = v;
  __syncthreads();
  if (tid == 0) {
    float ld = sm[0] + sm[1] + sm[2] + sm[3];
    out[0] = 0.5f * (lg * 0.125f) + 0.5f * (ld * (1.0f / 6272.0f));
  }
}

extern "C" void kernel_launch(void* const* d_in, const int* in_sizes, int n_in,
                              void* d_out, int out_size, void* d_ws, size_t ws_size,
                              hipStream_t stream) {
  (void)in_sizes; (void)n_in; (void)out_size; (void)ws_size;
  const float* feat_q = (const float*)d_in[0];
  const float* feat_k = (const float*)d_in[1];
  const float* Wg1 = (const float*)d_in[2];
  const float* bg1 = (const float*)d_in[3];
  const float* Wg2 = (const float*)d_in[4];
  const float* bg2 = (const float*)d_in[5];
  const float* Wd1 = (const float*)d_in[6];
  const float* bd1 = (const float*)d_in[7];
  const float* Wd2 = (const float*)d_in[8];
  const float* bd2 = (const float*)d_in[9];
  const float* mWg1 = (const float*)d_in[10];
  const float* mbg1 = (const float*)d_in[11];
  const float* mWg2 = (const float*)d_in[12];
  const float* mbg2 = (const float*)d_in[13];
  const float* mWd1 = (const float*)d_in[14];
  const float* mbd1 = (const float*)d_in[15];
  const float* mWd2 = (const float*)d_in[16];
  const float* mbd2 = (const float*)d_in[17];
  const float* queue = (const float*)d_in[18];
  float* out = (float*)d_out;

  (void)hipFuncSetAttribute(reinterpret_cast<const void*>(&k_gemm256),
                            hipFuncAttributeMaxDynamicSharedMemorySize, 131072);

  char* ws = (char*)d_ws;
  size_t off = 0;
  auto alloc = [&](size_t bytes) -> void* {
    void* p = (void*)(ws + off);
    off += (bytes + 255) & ~(size_t)255;
    return p;
  };

  ushort* featq_bf = (ushort*)alloc(6272ull * 1024 * 2);
  ushort* featk_bf = (ushort*)alloc(6272ull * 1024 * 2);
  ushort* Wd1t = (ushort*)alloc(2048ull * 1024 * 2);
  ushort* mWd1t = (ushort*)alloc(2048ull * 1024 * 2);
  ushort* Wd2t = (ushort*)alloc(128ull * 2048 * 2);
  ushort* mWd2t = (ushort*)alloc(128ull * 2048 * 2);
  ushort* h_bf = (ushort*)alloc(6272ull * 2048 * 2);
  float* e2part = (float*)alloc(4ull * 6272 * 128 * 4);
  float* qd = (float*)alloc(6272ull * 128 * 4);
  float* kd = (float*)alloc(6272ull * 128 * 4);
  ushort* qd_bf = (ushort*)alloc(6272ull * 128 * 2);
  ushort* kd_bf = (ushort*)alloc(6272ull * 128 * 2);
  ushort* matched_bf = (ushort*)alloc(6272ull * 128 * 2);
  float* psum = (float*)alloc(6272ull * 49 * 4);
  float* pval = (float*)alloc(6272ull * 7 * 4);
  int* pidx = (int*)alloc(6272ull * 7 * 4);
  int* idxf = (int*)alloc(6272ull * 4);
  float* gpart = (float*)alloc(8ull * 112 * 1024 * 4);
  float* gq = (float*)alloc(8ull * 1024 * 4);
  float* gk = (float*)alloc(8ull * 1024 * 4);
  float* part1 = (float*)alloc(16ull * 8 * 2048 * 4);
  float* hgq = (float*)alloc(8ull * 2048 * 4);
  float* hgk = (float*)alloc(8ull * 2048 * 4);
  float* part2q = (float*)alloc(32ull * 8 * 128 * 4);
  float* part2k = (float*)alloc(32ull * 8 * 128 * 4);
  float* qg = (float*)alloc(8ull * 128 * 4);
  float* kg = (float*)alloc(8ull * 128 * 4);
  float* l_pos = (float*)alloc(8ull * 4);
  float* qpart_s = (float*)alloc(256ull * 8 * 4);
  float* diff = (float*)alloc(6272ull * 4);

  k_cvt_pool<<<dim3(112, 8), 256, 0, stream>>>(feat_q, featq_bf, gpart);
  k_gpool_fin<<<32, 256, 0, stream>>>(gpart, gq);
  k_cvt_pool<<<dim3(112, 8), 256, 0, stream>>>(feat_k, featk_bf, gpart);
  k_gpool_fin<<<32, 256, 0, stream>>>(gpart, gk);

  k_transpose_cvt<<<dim3(64, 32), 256, 0, stream>>>(Wd1, Wd1t, 1024, 2048);
  k_transpose_cvt<<<dim3(64, 32), 256, 0, stream>>>(mWd1, mWd1t, 1024, 2048);
  k_transpose_cvt<<<dim3(4, 64), 256, 0, stream>>>(Wd2, Wd2t, 2048, 128);
  k_transpose_cvt<<<dim3(4, 64), 256, 0, stream>>>(mWd2, mWd2t, 2048, 128);

  k_dense1_part<<<dim3(8, 16), 256, 0, stream>>>(gq, Wg1, part1);
  k_dense1_fin<<<64, 256, 0, stream>>>(part1, bg1, hgq);
  k_dense2_part<<<32, 128, 0, stream>>>(hgq, Wg2, part2q);
  k_dense1_part<<<dim3(8, 16), 256, 0, stream>>>(gk, mWg1, part1);
  k_dense1_fin<<<64, 256, 0, stream>>>(part1, mbg1, hgk);
  k_dense2_part<<<32, 128, 0, stream>>>(hgk, mWg2, part2k);
  k_head_fin<<<8, 64, 0, stream>>>(part2q, part2k, bg2, mbg2, qg, kg, l_pos);

  // E1 (256^2 8-wave counted-vmcnt): h = relu(feat @ Wd1 + bd1)
  k_gemm256<<<dim3(8, 25), 512, 131072, stream>>>(featq_bf, Wd1t, bd1, h_bf, 6272, 1024, 2048);
  k_gemm_abt<4><<<dim3(1, 49, 4), 256, 0, stream>>>(h_bf, Wd2t, nullptr, e2part, nullptr,
                                                    6272, 128, 512, 2048, 2048, 128, 802816, 0.f, 512, 512);
  k_l2n_rows<<<1568, 256, 0, stream>>>(e2part, bd2, qd, qd_bf, 6272);

  k_gemm256<<<dim3(8, 25), 512, 131072, stream>>>(featk_bf, mWd1t, mbd1, h_bf, 6272, 1024, 2048);
  k_gemm_abt<4><<<dim3(1, 49, 4), 256, 0, stream>>>(h_bf, mWd2t, nullptr, e2part, nullptr,
                                                    6272, 128, 512, 2048, 2048, 128, 802816, 0.f, 512, 512);
  k_l2n_rows<<<1568, 256, 0, stream>>>(e2part, mbd2, kd, kd_bf, 6272);

  k_gemm_abt<3><<<dim3(7, 7, 8), 256, 0, stream>>>(qd_bf, kd_bf, nullptr, pval, pidx,
                                                   784, 784, 128, 128, 128, 0, 7, 0.f,
                                                   784l * 128, 784l * 128);
  k_argmax_gather<<<6272, 64, 0, stream>>>(pval, pidx, kd_bf, matched_bf, idxf);

  k_gemm_abt<2><<<dim3(49, 49, 1), 256, 0, stream>>>(qd_bf, matched_bf, nullptr, psum, nullptr,
                                                     6272, 6272, 128, 128, 128, 0, 49,
                                                     TAU_INV * L2E, 0, 0);

  k_queue_nce<<<256, 256, 0, stream>>>(queue, qg, qpart_s);

  k_row_lse<<<1568, 256, 0, stream>>>(psum, idxf, qd, kd, diff);
  k_final<<<1, 256, 0, stream>>>(qpart_s, l_pos, diff, out);
}

// Round 9
// 230.791 us; speedup vs baseline: 1.2605x; 1.2605x over previous
//
#include <hip/hip_runtime.h>
#include <cstdint>

#define TAU_INV 5.0f
#define L2E 1.4426950408889634f

using ushort = unsigned short;
typedef __attribute__((ext_vector_type(8))) short s16x8;
typedef __attribute__((ext_vector_type(4))) float f32x4;

static __device__ __forceinline__ ushort f2bf(float x) {
  unsigned u = __float_as_uint(x);
  return (ushort)((u + 0x7fffu + ((u >> 16) & 1u)) >> 16);
}

static __device__ __forceinline__ float fexp2(float x) {
#if __has_builtin(__builtin_amdgcn_exp2f)
  return __builtin_amdgcn_exp2f(x);
#else
  return exp2f(x);
#endif
}

static __device__ __forceinline__ void gload_lds16(const void* g, void* l) {
  __builtin_amdgcn_global_load_lds(
      reinterpret_cast<const __attribute__((address_space(1))) void*>(
          reinterpret_cast<uintptr_t>(g)),
      reinterpret_cast<__attribute__((address_space(3))) void*>(
          (unsigned)reinterpret_cast<uintptr_t>(l)),
      16, 0, 0);
}

// bijective XCD-chunked swizzle of the (y*gx+x) tile space (m204 formula)
static __device__ __forceinline__ void xcd_swizzle(int gx, int gy, int& bx, int& by) {
  int nwg = gx * gy;
  int flat = by * gx + bx;
  int q = nwg >> 3, r = nwg & 7;
  int xcd = flat & 7, sl = flat >> 3;
  int tile = (xcd < r ? xcd * (q + 1) : r * (q + 1) + (xcd - r) * q) + sl;
  by = tile / gx;
  bx = tile - by * gx;
}

// ---------------- fused f32->bf16 convert + partial channel pool (q+k batched) --------
__global__ void k_cvt_pool(const float* __restrict__ fq, const float* __restrict__ fk,
                           ushort* __restrict__ obf, float* __restrict__ gpart) {
  int br = blockIdx.y >> 3, b = blockIdx.y & 7, pc = blockIdx.x, t = threadIdx.x;
  const float* feat = br ? fk : fq;
  const float* fp = feat + ((size_t)b * 784 + (size_t)pc * 7) * 1024;
  ushort* op = obf + (size_t)br * 6422528 + ((size_t)b * 784 + (size_t)pc * 7) * 1024;
  float4 acc = {0.f, 0.f, 0.f, 0.f};
#pragma unroll
  for (int p = 0; p < 7; ++p) {
    float4 v = ((const float4*)(fp + (size_t)p * 1024))[t];
    acc.x += v.x; acc.y += v.y; acc.z += v.z; acc.w += v.w;
    ushort4 r;
    r.x = f2bf(v.x); r.y = f2bf(v.y); r.z = f2bf(v.z); r.w = f2bf(v.w);
    ((ushort4*)(op + (size_t)p * 1024))[t] = r;
  }
  ((float4*)(gpart + ((size_t)blockIdx.y * 112 + pc) * 1024))[t] = acc;
}

__global__ void k_gpool_fin(const float* __restrict__ gpart, float* __restrict__ g) {
  int idx = blockIdx.x * 256 + threadIdx.x;   // 16384: [br*8+b][c]
  int bb = idx >> 10, c = idx & 1023;
  float s = 0.f;
#pragma unroll 4
  for (int pc = 0; pc < 112; ++pc) s += gpart[((size_t)bb * 112 + pc) * 1024 + c];
  g[idx] = s * (1.0f / 784.0f);
}

__global__ void k_dense1_part(const float* __restrict__ g, const float* __restrict__ W0,
                              const float* __restrict__ W1, float* __restrict__ part1) {
  int br = blockIdx.z;
  const float* gb = g + (size_t)br * 8192;
  const float* W = br ? W1 : W0;
  float* p1 = part1 + (size_t)br * 262144;
  int d = blockIdx.x * 256 + threadIdx.x;
  int k0 = blockIdx.y * 64;
  __shared__ float gs[512];
  for (int i = threadIdx.x; i < 512; i += 256) gs[i] = gb[(i >> 6) * 1024 + k0 + (i & 63)];
  __syncthreads();
  float acc[8] = {};
  for (int kk = 0; kk < 64; ++kk) {
    float w = W[(size_t)(k0 + kk) * 2048 + d];
#pragma unroll
    for (int b = 0; b < 8; ++b) acc[b] += gs[b * 64 + kk] * w;
  }
#pragma unroll
  for (int b = 0; b < 8; ++b) p1[((size_t)blockIdx.y * 8 + b) * 2048 + d] = acc[b];
}

// fused dense1-finalize + dense2 partial; grid (32, 2), block 128
__global__ void k_d12(const float* __restrict__ part1, const float* __restrict__ b10,
                      const float* __restrict__ b11, const float* __restrict__ W20,
                      const float* __restrict__ W21, float* __restrict__ part2) {
  int br = blockIdx.y, k0 = blockIdx.x * 64;
  const float* p1 = part1 + (size_t)br * 262144;
  const float* b1 = br ? b11 : b10;
  const float* W2 = br ? W21 : W20;
  float* p2 = part2 + (size_t)br * 32768;
  __shared__ float hs[512];
  for (int i = threadIdx.x; i < 512; i += 128) {
    int b = i >> 6, kk = i & 63;
    float s = b1[k0 + kk];
#pragma unroll
    for (int ks = 0; ks < 16; ++ks) s += p1[((size_t)ks * 8 + b) * 2048 + k0 + kk];
    hs[i] = fmaxf(s, 0.f);
  }
  __syncthreads();
  int d = threadIdx.x;
  float acc[8] = {};
  for (int kk = 0; kk < 64; ++kk) {
    float w = W2[(size_t)(k0 + kk) * 128 + d];
#pragma unroll
    for (int b = 0; b < 8; ++b) acc[b] += hs[b * 64 + kk] * w;
  }
#pragma unroll
  for (int b = 0; b < 8; ++b) p2[((size_t)blockIdx.x * 8 + b) * 128 + d] = acc[b];
}

__global__ void k_head_fin(const float* __restrict__ p2q, const float* __restrict__ p2k,
                           const float* __restrict__ bq, const float* __restrict__ bk,
                           float* __restrict__ qg, float* __restrict__ kg,
                           float* __restrict__ lpos) {
  int b = blockIdx.x, lane = threadIdx.x;
  float q0 = bq[lane], q1 = bq[lane + 64];
  float k0 = bk[lane], k1 = bk[lane + 64];
#pragma unroll
  for (int s = 0; s < 32; ++s) {
    size_t base = ((size_t)s * 8 + b) * 128;
    q0 += p2q[base + lane]; q1 += p2q[base + lane + 64];
    k0 += p2k[base + lane]; k1 += p2k[base + lane + 64];
  }
  float sq = q0 * q0 + q1 * q1, sk = k0 * k0 + k1 * k1;
#pragma unroll
  for (int d = 1; d < 64; d <<= 1) { sq += __shfl_xor(sq, d); sk += __shfl_xor(sk, d); }
  float rq = 1.0f / sqrtf(fmaxf(sq, 1e-12f));
  float rk = 1.0f / sqrtf(fmaxf(sk, 1e-12f));
  q0 *= rq; q1 *= rq; k0 *= rk; k1 *= rk;
  qg[b * 128 + lane] = q0; qg[b * 128 + 64 + lane] = q1;
  kg[b * 128 + lane] = k0; kg[b * 128 + 64 + lane] = k1;
  float lp = q0 * k0 + q1 * k1;
#pragma unroll
  for (int d = 1; d < 64; d <<= 1) lp += __shfl_xor(lp, d);
  if (lane == 0) lpos[b] = lp;
}

// ---------------- transpose + convert, q+k batched via z ----------------
__global__ void k_transpose_cvt(const float* __restrict__ W0, const float* __restrict__ W1,
                                ushort* __restrict__ Wt, int K, int N, size_t strideOut) {
  const float* W = blockIdx.z ? W1 : W0;
  ushort* o = Wt + (size_t)blockIdx.z * strideOut;
  __shared__ float tile[32][33];
  int n0 = blockIdx.x * 32, k0 = blockIdx.y * 32;
  int tx = threadIdx.x & 31, ty = threadIdx.x >> 5;
#pragma unroll
  for (int i = 0; i < 32; i += 8)
    tile[ty + i][tx] = W[(size_t)(k0 + ty + i) * N + n0 + tx];
  __syncthreads();
#pragma unroll
  for (int i = 0; i < 32; i += 8)
    o[(size_t)(n0 + ty + i) * K + k0 + tx] = f2bf(tile[tx][ty + i]);
}

// ============ E1: 128x128 2-phase dbuf GEMM, q+k batched (grid 16,49,2) ============
__global__ __launch_bounds__(256) void k_gemm_e1(
    const ushort* __restrict__ A, long sA, const ushort* __restrict__ B, long sB,
    const float* __restrict__ bias0, const float* __restrict__ bias1,
    ushort* __restrict__ O, long sO, int K, int ldOut) {
  __shared__ unsigned char smem[65536];
  const int tid = threadIdx.x;
  int bx = blockIdx.x, by = blockIdx.y;
  const int bz = blockIdx.z;
  xcd_swizzle(gridDim.x, gridDim.y, bx, by);
  const ushort* Ab = A + (size_t)bz * sA;
  const ushort* Bb = B + (size_t)bz * sB;
  const float* bias = bz ? bias1 : bias0;
  ushort* Ob = O + (size_t)bz * sO;
  const int mBase = by * 128, nBase = bx * 128;
  const int lane = tid & 63;
  const int wid = tid >> 6;
  const int wid_u = __builtin_amdgcn_readfirstlane(wid);
  const int wm = wid >> 1, wn = wid & 1;
  const int lg = lane >> 4, li = lane & 15;
  const int lrow = lane >> 3, lchunk = lane & 7;

  const ushort* aSrc[4];
  const ushort* bSrc[4];
  int ldsOff[4];
#pragma unroll
  for (int j = 0; j < 4; ++j) {
    int r = wid_u * 32 + j * 8 + lrow;
    int gc = (lchunk ^ lrow) << 3;
    aSrc[j] = Ab + (size_t)(mBase + r) * K + gc;
    bSrc[j] = Bb + (size_t)(nBase + r) * K + gc;
    ldsOff[j] = (wid_u * 32 + j * 8) * 128;
  }
  f32x4 acc[4][4] = {};

  auto STAGE = [&](int buf, int k0) {
    unsigned base = (unsigned)buf * 32768u;
#pragma unroll
    for (int j = 0; j < 4; ++j) {
      gload_lds16(aSrc[j] + k0, smem + base + ldsOff[j]);
      gload_lds16(bSrc[j] + k0, smem + base + 16384 + ldsOff[j]);
    }
  };

  const int nt = K >> 6;
  STAGE(0, 0);
  __syncthreads();
  for (int t = 0; t < nt; ++t) {
    if (t + 1 < nt) STAGE((t + 1) & 1, (t + 1) << 6);
    const unsigned char* As = smem + (t & 1) * 32768;
    const unsigned char* Bs = As + 16384;
#pragma unroll
    for (int ks = 0; ks < 2; ++ks) {
      s16x8 af[4], bfr[4];
#pragma unroll
      for (int mi = 0; mi < 4; ++mi) {
        int r = wm * 64 + mi * 16 + li;
        af[mi] = *(const s16x8*)(const void*)(As + r * 128 + ((ks * 64 + lg * 16) ^ ((r & 7) << 4)));
      }
#pragma unroll
      for (int ni = 0; ni < 4; ++ni) {
        int c = wn * 64 + ni * 16 + li;
        bfr[ni] = *(const s16x8*)(const void*)(Bs + c * 128 + ((ks * 64 + lg * 16) ^ ((c & 7) << 4)));
      }
#pragma unroll
      for (int mi = 0; mi < 4; ++mi)
#pragma unroll
        for (int ni = 0; ni < 4; ++ni)
          acc[mi][ni] = __builtin_amdgcn_mfma_f32_16x16x32_bf16(af[mi], bfr[ni], acc[mi][ni], 0, 0, 0);
    }
    __syncthreads();
  }

#pragma unroll
  for (int ni = 0; ni < 4; ++ni) {
    int c = nBase + wn * 64 + ni * 16 + li;
    float bv = bias[c];
#pragma unroll
    for (int mi = 0; mi < 4; ++mi) {
#pragma unroll
      for (int rg = 0; rg < 4; ++rg) {
        int r = mBase + wm * 64 + mi * 16 + lg * 4 + rg;
        float v = fmaxf(acc[mi][ni][rg] + bv, 0.f);
        Ob[(size_t)r * ldOut + c] = f2bf(v);
      }
    }
  }
}

// ---------------- MFMA GEMM template: 128x128 2-phase dbuf ----------------
// EPI 2: per-row sum(exp(acc*scale)); EPI 3: (max,argmax), bz=batch
// EPI 4: raw f32, bz = branch*4 + kslice (A/B offset branch*s? + slice*Kloop)
template <int EPI>
__global__ __launch_bounds__(256) void k_gemm_abt(
    const ushort* __restrict__ A, const ushort* __restrict__ B,
    const float* __restrict__ bias, void* __restrict__ o0, void* __restrict__ o1,
    int Mvalid, int Nvalid, int Kloop, int lda, int ldb, int ldOut, int ntiles,
    float scale, long sA, long sB) {
  __shared__ unsigned char smem[65536];
  const int tid = threadIdx.x;
  int bx = blockIdx.x, by = blockIdx.y;
  const int bz = blockIdx.z;
  xcd_swizzle(gridDim.x, gridDim.y, bx, by);
  const ushort* Ab;
  const ushort* Bb;
  if constexpr (EPI == 4) {
    Ab = A + (size_t)(bz >> 2) * sA + (size_t)(bz & 3) * Kloop;
    Bb = B + (size_t)(bz >> 2) * sB + (size_t)(bz & 3) * Kloop;
  } else {
    Ab = A + (size_t)bz * sA;
    Bb = B + (size_t)bz * sB;
  }
  const int mBase = by * 128, nBase = bx * 128;
  const int lane = tid & 63;
  const int wid = tid >> 6;
  const int wid_u = __builtin_amdgcn_readfirstlane(wid);
  const int wm = wid >> 1, wn = wid & 1;
  const int lg = lane >> 4, li = lane & 15;
  const int lrow = lane >> 3, lchunk = lane & 7;

  const ushort* aSrc[4];
  const ushort* bSrc[4];
  int ldsOff[4];
#pragma unroll
  for (int j = 0; j < 4; ++j) {
    int r = wid_u * 32 + j * 8 + lrow;
    int gc = (lchunk ^ lrow) << 3;
    int ga = mBase + r; ga = ga < Mvalid ? ga : Mvalid - 1;
    int gb = nBase + r; gb = gb < Nvalid ? gb : Nvalid - 1;
    aSrc[j] = Ab + (size_t)ga * lda + gc;
    bSrc[j] = Bb + (size_t)gb * ldb + gc;
    ldsOff[j] = (wid_u * 32 + j * 8) * 128;
  }
  f32x4 acc[4][4] = {};

  auto STAGE = [&](int buf, int k0) {
    unsigned base = (unsigned)buf * 32768u;
#pragma unroll
    for (int j = 0; j < 4; ++j) {
      gload_lds16(aSrc[j] + k0, smem + base + ldsOff[j]);
      gload_lds16(bSrc[j] + k0, smem + base + 16384 + ldsOff[j]);
    }
  };

  const int nt = Kloop >> 6;
  STAGE(0, 0);
  __syncthreads();
  for (int t = 0; t < nt; ++t) {
    if (t + 1 < nt) STAGE((t + 1) & 1, (t + 1) << 6);
    const unsigned char* As = smem + (t & 1) * 32768;
    const unsigned char* Bs = As + 16384;
#pragma unroll
    for (int ks = 0; ks < 2; ++ks) {
      s16x8 af[4], bfr[4];
#pragma unroll
      for (int mi = 0; mi < 4; ++mi) {
        int r = wm * 64 + mi * 16 + li;
        af[mi] = *(const s16x8*)(const void*)(As + r * 128 + ((ks * 64 + lg * 16) ^ ((r & 7) << 4)));
      }
#pragma unroll
      for (int ni = 0; ni < 4; ++ni) {
        int c = wn * 64 + ni * 16 + li;
        bfr[ni] = *(const s16x8*)(const void*)(Bs + c * 128 + ((ks * 64 + lg * 16) ^ ((c & 7) << 4)));
      }
#pragma unroll
      for (int mi = 0; mi < 4; ++mi)
#pragma unroll
        for (int ni = 0; ni < 4; ++ni)
          acc[mi][ni] = __builtin_amdgcn_mfma_f32_16x16x32_bf16(af[mi], bfr[ni], acc[mi][ni], 0, 0, 0);
    }
    __syncthreads();
  }

  if constexpr (EPI == 4) {
#pragma unroll
    for (int ni = 0; ni < 4; ++ni) {
      int c = nBase + wn * 64 + ni * 16 + li;
#pragma unroll
      for (int mi = 0; mi < 4; ++mi)
#pragma unroll
        for (int rg = 0; rg < 4; ++rg) {
          int r = mBase + wm * 64 + mi * 16 + lg * 4 + rg;
          if (r < Mvalid && c < Nvalid)
            ((float*)o0)[(size_t)bz * ntiles + (size_t)r * ldOut + c] = acc[mi][ni][rg];
        }
    }
  } else if constexpr (EPI == 2) {
    __syncthreads();
    float* reds = (float*)(void*)smem;   // [128][2]
#pragma unroll
    for (int mi = 0; mi < 4; ++mi)
#pragma unroll
      for (int rg = 0; rg < 4; ++rg) {
        float s = fexp2(acc[mi][0][rg] * scale) + fexp2(acc[mi][1][rg] * scale) +
                  fexp2(acc[mi][2][rg] * scale) + fexp2(acc[mi][3][rg] * scale);
#pragma unroll
        for (int d = 1; d < 16; d <<= 1) s += __shfl_xor(s, d);
        int rl = wm * 64 + mi * 16 + lg * 4 + rg;
        if (li == 0) reds[rl * 2 + wn] = s;
      }
    __syncthreads();
    if (tid < 128) {
      size_t idx = (size_t)(mBase + tid) * ntiles + bx;
      ((float*)o0)[idx] = reds[tid * 2] + reds[tid * 2 + 1];
    }
  } else if constexpr (EPI == 3) {
    __syncthreads();
    float* redv = (float*)(void*)smem;
    int* redi = (int*)(void*)(smem + 1024);
#pragma unroll
    for (int mi = 0; mi < 4; ++mi)
#pragma unroll
      for (int rg = 0; rg < 4; ++rg) {
        float bv = -3.4e38f;
        int bi = 0x7fffffff;
#pragma unroll
        for (int ni = 0; ni < 4; ++ni) {
          int c = nBase + wn * 64 + ni * 16 + li;
          float v = (c < Nvalid) ? acc[mi][ni][rg] : -3.4e38f;
          if (v > bv || (v == bv && c < bi)) { bv = v; bi = c; }
        }
#pragma unroll
        for (int d = 1; d < 16; d <<= 1) {
          float ov = __shfl_xor(bv, d);
          int oi = __shfl_xor(bi, d);
          if (ov > bv || (ov == bv && oi < bi)) { bv = ov; bi = oi; }
        }
        int rl = wm * 64 + mi * 16 + lg * 4 + rg;
        if (li == 0) { redv[rl * 2 + wn] = bv; redi[rl * 2 + wn] = bi; }
      }
    __syncthreads();
    if (tid < 128) {
      int r = mBase + tid;
      if (r < Mvalid) {
        float v0 = redv[tid * 2], v1 = redv[tid * 2 + 1];
        int i0 = redi[tid * 2], i1 = redi[tid * 2 + 1];
        float v = v0; int bi2 = i0;
        if (v1 > v || (v1 == v && i1 < bi2)) { v = v1; bi2 = i1; }
        size_t idx = (size_t)(bz * Mvalid + r) * ntiles + bx;
        ((float*)o0)[idx] = v;
        ((int*)o1)[idx] = bi2;
      }
    }
  }
}

// ---------------- sum 4 K-slice partials + bias, l2-normalize; q+k batched -----------
__global__ void k_l2n_rows(const float* __restrict__ part, const float* __restrict__ bias0,
                           const float* __restrict__ bias1, float* __restrict__ of,
                           ushort* __restrict__ ob) {
  int br = blockIdx.y;
  const float* p = part + (size_t)br * 3211264;
  const float* bias = br ? bias1 : bias0;
  float* o = of + (size_t)br * 802816;
  ushort* o2 = ob + (size_t)br * 802816;
  int row = blockIdx.x * 4 + (threadIdx.x >> 6);
  int lane = threadIdx.x & 63;
  size_t i0 = (size_t)row * 128 + lane;
  const size_t SL = 802816;
  float v0 = bias[lane]      + p[i0]      + p[SL + i0]      + p[2 * SL + i0]      + p[3 * SL + i0];
  float v1 = bias[lane + 64] + p[i0 + 64] + p[SL + i0 + 64] + p[2 * SL + i0 + 64] + p[3 * SL + i0 + 64];
  float ss = v0 * v0 + v1 * v1;
#pragma unroll
  for (int d = 1; d < 64; d <<= 1) ss += __shfl_xor(ss, d);
  float r = 1.0f / sqrtf(fmaxf(ss, 1e-12f));
  o[i0] = v0 * r;
  o[i0 + 64] = v1 * r;
  o2[i0] = f2bf(v0 * r);
  o2[i0 + 64] = f2bf(v1 * r);
}

// ---------------- argmax finalize + gather ----------------
__global__ void k_argmax_gather(const float* __restrict__ pval, const int* __restrict__ pidx,
                                const ushort* __restrict__ kd_bf, ushort* __restrict__ matched_bf,
                                int* __restrict__ idxf) {
  int n = blockIdx.x;
  int b = n / 784;
  float bv = pval[(size_t)n * 7];
  int bi = pidx[(size_t)n * 7];
#pragma unroll
  for (int t = 1; t < 7; ++t) {
    float v = pval[(size_t)n * 7 + t];
    int i2 = pidx[(size_t)n * 7 + t];
    if (v > bv) { bv = v; bi = i2; }
  }
  int lane = threadIdx.x;
  if (lane == 0) idxf[n] = bi;
  const ushort* src = kd_bf + (size_t)(b * 784 + bi) * 128;
  ushort* dst = matched_bf + (size_t)n * 128;
  dst[lane] = src[lane];
  dst[lane + 64] = src[lane + 64];
}

// ---------------- queue InfoNCE partials (max-free) ----------------
__global__ __launch_bounds__(256) void k_queue_nce(const float* __restrict__ queue,
                                                   const float* __restrict__ qg,
                                                   float* __restrict__ ps) {
  __shared__ float qs[1024];
  int tid = threadIdx.x;
  for (int i = tid; i < 1024; i += 256) qs[i] = qg[i];
  __syncthreads();
  int r = blockIdx.x * 256 + tid;
  const float* qr = queue + (size_t)r * 128;
  float a[8] = {0, 0, 0, 0, 0, 0, 0, 0};
  for (int j = 0; j < 128; j += 4) {
    float4 v = *(const float4*)(const void*)(qr + j);
#pragma unroll
    for (int b = 0; b < 8; ++b)
      a[b] += v.x * qs[b * 128 + j] + v.y * qs[b * 128 + j + 1] +
              v.z * qs[b * 128 + j + 2] + v.w * qs[b * 128 + j + 3];
  }
  __shared__ float lssum[8][4];
  int lane = tid & 63, w = tid >> 6;
#pragma unroll
  for (int b = 0; b < 8; ++b) {
    float s = fexp2(a[b] * (TAU_INV * L2E));
#pragma unroll
    for (int d = 1; d < 64; d <<= 1) s += __shfl_xor(s, d);
    if (lane == 0) lssum[b][w] = s;
  }
  __syncthreads();
  if (tid < 8) {
    int b = tid;
    ps[blockIdx.x * 8 + b] = lssum[b][0] + lssum[b][1] + lssum[b][2] + lssum[b][3];
  }
}

// ---------------- per-row: sum 49 partials -> log + pos dot ----------------
__global__ void k_row_lse(const float* __restrict__ psum, const int* __restrict__ idxf,
                          const float* __restrict__ qd, const float* __restrict__ kd,
                          float* __restrict__ diff) {
  int n = blockIdx.x * 4 + (threadIdx.x >> 6);
  int lane = threadIdx.x & 63;
  float s = (lane < 49) ? psum[(size_t)n * 49 + lane] : 0.f;
#pragma unroll
  for (int d = 1; d < 64; d <<= 1) s += __shfl_xor(s, d);
  int b = n / 784;
  int mr = b * 784 + idxf[n];
  float pos = qd[(size_t)n * 128 + lane] * kd[(size_t)mr * 128 + lane] +
              qd[(size_t)n * 128 + 64 + lane] * kd[(size_t)mr * 128 + 64 + lane];
#pragma unroll
  for (int d = 1; d < 64; d <<= 1) pos += __shfl_xor(pos, d);
  if (lane == 0) diff[n] = logf(s) - pos * TAU_INV;
}

// ---------------- final combine (max-free) ----------------
__global__ void k_final(const float* __restrict__ ps, const float* __restrict__ lpos,
                        const float* __restrict__ diff, float* __restrict__ out) {
  int tid = threadIdx.x;
  int lane = tid & 63, w = tid >> 6;
  __shared__ float sm[4];
  float lg = 0.f;
  for (int b = 0; b < 8; ++b) {
    float s = ps[tid * 8 + b];
#pragma unroll
    for (int d = 1; d < 64; d <<= 1) s += __shfl_xor(s, d);
    if (lane == 0) sm[w] = s;
    __syncthreads();
    if (tid == 0) {
      float S = sm[0] + sm[1] + sm[2] + sm[3];
      float lp = lpos[b] * TAU_INV;
      S += fexp2(lp * L2E);
      lg += logf(S) - lp;
    }
    __syncthreads();
  }
  float v = 0.f;
  for (int i = tid; i < 6272; i += 256) v += diff[i];
#pragma unroll
  for (int d = 1; d < 64; d <<= 1) v += __shfl_xor(v, d);
  if (lane == 0) sm[w] = v;
  __syncthreads();
  if (tid == 0) {
    float ld = sm[0] + sm[1] + sm[2] + sm[3];
    out[0] = 0.5f * (lg * 0.125f) + 0.5f * (ld * (1.0f / 6272.0f));
  }
}

extern "C" void kernel_launch(void* const* d_in, const int* in_sizes, int n_in,
                              void* d_out, int out_size, void* d_ws, size_t ws_size,
                              hipStream_t stream) {
  (void)in_sizes; (void)n_in; (void)out_size; (void)ws_size;
  const float* feat_q = (const float*)d_in[0];
  const float* feat_k = (const float*)d_in[1];
  const float* Wg1 = (const float*)d_in[2];
  const float* bg1 = (const float*)d_in[3];
  const float* Wg2 = (const float*)d_in[4];
  const float* bg2 = (const float*)d_in[5];
  const float* Wd1 = (const float*)d_in[6];
  const float* bd1 = (const float*)d_in[7];
  const float* Wd2 = (const float*)d_in[8];
  const float* bd2 = (const float*)d_in[9];
  const float* mWg1 = (const float*)d_in[10];
  const float* mbg1 = (const float*)d_in[11];
  const float* mWg2 = (const float*)d_in[12];
  const float* mbg2 = (const float*)d_in[13];
  const float* mWd1 = (const float*)d_in[14];
  const float* mbd1 = (const float*)d_in[15];
  const float* mWd2 = (const float*)d_in[16];
  const float* mbd2 = (const float*)d_in[17];
  const float* queue = (const float*)d_in[18];
  float* out = (float*)d_out;

  char* ws = (char*)d_ws;
  size_t off = 0;
  auto alloc = [&](size_t bytes) -> void* {
    void* p = (void*)(ws + off);
    off += (bytes + 255) & ~(size_t)255;
    return p;
  };

  // joint (q,k) buffers; branch element-strides in comments
  ushort* feat_bf = (ushort*)alloc(2ull * 6272 * 1024 * 2);   // +6422528
  ushort* Wd1t2 = (ushort*)alloc(2ull * 2048 * 1024 * 2);     // +2097152
  ushort* Wd2t2 = (ushort*)alloc(2ull * 128 * 2048 * 2);      // +262144
  ushort* h_bf2 = (ushort*)alloc(2ull * 6272 * 2048 * 2);     // +12845056
  float* e2part2 = (float*)alloc(2ull * 4 * 6272 * 128 * 4);  // +3211264
  float* qdkd = (float*)alloc(2ull * 6272 * 128 * 4);         // +802816
  ushort* qdkd_bf = (ushort*)alloc(2ull * 6272 * 128 * 2);    // +802816
  ushort* matched_bf = (ushort*)alloc(6272ull * 128 * 2);
  float* psum = (float*)alloc(6272ull * 49 * 4);
  float* pval = (float*)alloc(6272ull * 7 * 4);
  int* pidx = (int*)alloc(6272ull * 7 * 4);
  int* idxf = (int*)alloc(6272ull * 4);
  float* gpart = (float*)alloc(16ull * 112 * 1024 * 4);
  float* g2 = (float*)alloc(2ull * 8 * 1024 * 4);             // +8192
  float* part1 = (float*)alloc(2ull * 16 * 8 * 2048 * 4);     // +262144
  float* part2 = (float*)alloc(2ull * 32 * 8 * 128 * 4);      // +32768
  float* qg = (float*)alloc(8ull * 128 * 4);
  float* kg = (float*)alloc(8ull * 128 * 4);
  float* l_pos = (float*)alloc(8ull * 4);
  float* qpart_s = (float*)alloc(256ull * 8 * 4);
  float* diff = (float*)alloc(6272ull * 4);

  k_cvt_pool<<<dim3(112, 16), 256, 0, stream>>>(feat_q, feat_k, feat_bf, gpart);
  k_gpool_fin<<<64, 256, 0, stream>>>(gpart, g2);

  k_transpose_cvt<<<dim3(64, 32, 2), 256, 0, stream>>>(Wd1, mWd1, Wd1t2, 1024, 2048, 2097152);
  k_transpose_cvt<<<dim3(4, 64, 2), 256, 0, stream>>>(Wd2, mWd2, Wd2t2, 2048, 128, 262144);

  k_dense1_part<<<dim3(8, 16, 2), 256, 0, stream>>>(g2, Wg1, mWg1, part1);
  k_d12<<<dim3(32, 2), 128, 0, stream>>>(part1, bg1, mbg1, Wg2, mWg2, part2);
  k_head_fin<<<8, 64, 0, stream>>>(part2, part2 + 32768, bg2, mbg2, qg, kg, l_pos);

  // E1 batched: h = relu(feat @ Wd1 + b)
  k_gemm_e1<<<dim3(16, 49, 2), 256, 0, stream>>>(feat_bf, 6422528, Wd1t2, 2097152,
                                                 bd1, mbd1, h_bf2, 12845056, 1024, 2048);
  // E2 batched (branch x 4 K-slices)
  k_gemm_abt<4><<<dim3(1, 49, 8), 256, 0, stream>>>(h_bf2, Wd2t2, nullptr, e2part2, nullptr,
                                                    6272, 128, 512, 2048, 2048, 128, 802816,
                                                    0.f, 12845056, 262144);
  k_l2n_rows<<<dim3(1568, 2), 256, 0, stream>>>(e2part2, bd2, mbd2, qdkd, qdkd_bf);

  // dense correspondence
  k_gemm_abt<3><<<dim3(7, 7, 8), 256, 0, stream>>>(qdkd_bf, qdkd_bf + 802816, nullptr, pval, pidx,
                                                   784, 784, 128, 128, 128, 0, 7, 0.f,
                                                   784l * 128, 784l * 128);
  k_argmax_gather<<<6272, 64, 0, stream>>>(pval, pidx, qdkd_bf + 802816, matched_bf, idxf);

  // dense InfoNCE partials
  k_gemm_abt<2><<<dim3(49, 49, 1), 256, 0, stream>>>(qdkd_bf, matched_bf, nullptr, psum, nullptr,
                                                     6272, 6272, 128, 128, 128, 0, 49,
                                                     TAU_INV * L2E, 0, 0);

  k_queue_nce<<<256, 256, 0, stream>>>(queue, qg, qpart_s);

  k_row_lse<<<1568, 256, 0, stream>>>(psum, idxf, qdkd, qdkd + 802816, diff);
  k_final<<<1, 256, 0, stream>>>(qpart_s, l_pos, diff, out);
}

// Round 10
// 219.039 us; speedup vs baseline: 1.3281x; 1.0536x over previous
//
#include <hip/hip_runtime.h>
#include <cstdint>

#define TAU_INV 5.0f
#define L2E 1.4426950408889634f

using ushort = unsigned short;
typedef __attribute__((ext_vector_type(8))) short s16x8;
typedef __attribute__((ext_vector_type(4))) float f32x4;

static __device__ __forceinline__ ushort f2bf(float x) {
  unsigned u = __float_as_uint(x);
  return (ushort)((u + 0x7fffu + ((u >> 16) & 1u)) >> 16);
}

static __device__ __forceinline__ float fexp2(float x) {
#if __has_builtin(__builtin_amdgcn_exp2f)
  return __builtin_amdgcn_exp2f(x);
#else
  return exp2f(x);
#endif
}

static __device__ __forceinline__ void gload_lds16(const void* g, void* l) {
  __builtin_amdgcn_global_load_lds(
      reinterpret_cast<const __attribute__((address_space(1))) void*>(
          reinterpret_cast<uintptr_t>(g)),
      reinterpret_cast<__attribute__((address_space(3))) void*>(
          (unsigned)reinterpret_cast<uintptr_t>(l)),
      16, 0, 0);
}

// bijective XCD-chunked swizzle of the (y*gx+x) tile space (m204 formula)
static __device__ __forceinline__ void xcd_swizzle(int gx, int gy, int& bx, int& by) {
  int nwg = gx * gy;
  int flat = by * gx + bx;
  int q = nwg >> 3, r = nwg & 7;
  int xcd = flat & 7, sl = flat >> 3;
  int tile = (xcd < r ? xcd * (q + 1) : r * (q + 1) + (xcd - r) * q) + sl;
  by = tile / gx;
  bx = tile - by * gx;
}

// ---------------- fused f32->bf16 convert + partial channel pool (q+k batched) --------
__global__ void k_cvt_pool(const float* __restrict__ fq, const float* __restrict__ fk,
                           ushort* __restrict__ obf, float* __restrict__ gpart) {
  int br = blockIdx.y >> 3, b = blockIdx.y & 7, pc = blockIdx.x, t = threadIdx.x;
  const float* feat = br ? fk : fq;
  const float* fp = feat + ((size_t)b * 784 + (size_t)pc * 7) * 1024;
  ushort* op = obf + (size_t)br * 6422528 + ((size_t)b * 784 + (size_t)pc * 7) * 1024;
  float4 acc = {0.f, 0.f, 0.f, 0.f};
#pragma unroll
  for (int p = 0; p < 7; ++p) {
    float4 v = ((const float4*)(fp + (size_t)p * 1024))[t];
    acc.x += v.x; acc.y += v.y; acc.z += v.z; acc.w += v.w;
    ushort4 r;
    r.x = f2bf(v.x); r.y = f2bf(v.y); r.z = f2bf(v.z); r.w = f2bf(v.w);
    ((ushort4*)(op + (size_t)p * 1024))[t] = r;
  }
  ((float4*)(gpart + ((size_t)blockIdx.y * 112 + pc) * 1024))[t] = acc;
}

__global__ void k_gpool_fin(const float* __restrict__ gpart, float* __restrict__ g) {
  int idx = blockIdx.x * 256 + threadIdx.x;   // 16384: [br*8+b][c]
  int bb = idx >> 10, c = idx & 1023;
  float s = 0.f;
#pragma unroll 4
  for (int pc = 0; pc < 112; ++pc) s += gpart[((size_t)bb * 112 + pc) * 1024 + c];
  g[idx] = s * (1.0f / 784.0f);
}

__global__ void k_dense1_part(const float* __restrict__ g, const float* __restrict__ W0,
                              const float* __restrict__ W1, float* __restrict__ part1) {
  int br = blockIdx.z;
  const float* gb = g + (size_t)br * 8192;
  const float* W = br ? W1 : W0;
  float* p1 = part1 + (size_t)br * 262144;
  int d = blockIdx.x * 256 + threadIdx.x;
  int k0 = blockIdx.y * 64;
  __shared__ float gs[512];
  for (int i = threadIdx.x; i < 512; i += 256) gs[i] = gb[(i >> 6) * 1024 + k0 + (i & 63)];
  __syncthreads();
  float acc[8] = {};
  for (int kk = 0; kk < 64; ++kk) {
    float w = W[(size_t)(k0 + kk) * 2048 + d];
#pragma unroll
    for (int b = 0; b < 8; ++b) acc[b] += gs[b * 64 + kk] * w;
  }
#pragma unroll
  for (int b = 0; b < 8; ++b) p1[((size_t)blockIdx.y * 8 + b) * 2048 + d] = acc[b];
}

// fused dense1-finalize + dense2 partial; grid (32, 2), block 128
__global__ void k_d12(const float* __restrict__ part1, const float* __restrict__ b10,
                      const float* __restrict__ b11, const float* __restrict__ W20,
                      const float* __restrict__ W21, float* __restrict__ part2) {
  int br = blockIdx.y, k0 = blockIdx.x * 64;
  const float* p1 = part1 + (size_t)br * 262144;
  const float* b1 = br ? b11 : b10;
  const float* W2 = br ? W21 : W20;
  float* p2 = part2 + (size_t)br * 32768;
  __shared__ float hs[512];
  for (int i = threadIdx.x; i < 512; i += 128) {
    int b = i >> 6, kk = i & 63;
    float s = b1[k0 + kk];
#pragma unroll
    for (int ks = 0; ks < 16; ++ks) s += p1[((size_t)ks * 8 + b) * 2048 + k0 + kk];
    hs[i] = fmaxf(s, 0.f);
  }
  __syncthreads();
  int d = threadIdx.x;
  float acc[8] = {};
  for (int kk = 0; kk < 64; ++kk) {
    float w = W2[(size_t)(k0 + kk) * 128 + d];
#pragma unroll
    for (int b = 0; b < 8; ++b) acc[b] += hs[b * 64 + kk] * w;
  }
#pragma unroll
  for (int b = 0; b < 8; ++b) p2[((size_t)blockIdx.x * 8 + b) * 128 + d] = acc[b];
}

__global__ void k_head_fin(const float* __restrict__ p2q, const float* __restrict__ p2k,
                           const float* __restrict__ bq, const float* __restrict__ bk,
                           float* __restrict__ qg, float* __restrict__ kg,
                           float* __restrict__ lpos) {
  int b = blockIdx.x, lane = threadIdx.x;
  float q0 = bq[lane], q1 = bq[lane + 64];
  float k0 = bk[lane], k1 = bk[lane + 64];
#pragma unroll
  for (int s = 0; s < 32; ++s) {
    size_t base = ((size_t)s * 8 + b) * 128;
    q0 += p2q[base + lane]; q1 += p2q[base + lane + 64];
    k0 += p2k[base + lane]; k1 += p2k[base + lane + 64];
  }
  float sq = q0 * q0 + q1 * q1, sk = k0 * k0 + k1 * k1;
#pragma unroll
  for (int d = 1; d < 64; d <<= 1) { sq += __shfl_xor(sq, d); sk += __shfl_xor(sk, d); }
  float rq = 1.0f / sqrtf(fmaxf(sq, 1e-12f));
  float rk = 1.0f / sqrtf(fmaxf(sk, 1e-12f));
  q0 *= rq; q1 *= rq; k0 *= rk; k1 *= rk;
  qg[b * 128 + lane] = q0; qg[b * 128 + 64 + lane] = q1;
  kg[b * 128 + lane] = k0; kg[b * 128 + 64 + lane] = k1;
  float lp = q0 * k0 + q1 * k1;
#pragma unroll
  for (int d = 1; d < 64; d <<= 1) lp += __shfl_xor(lp, d);
  if (lane == 0) lpos[b] = lp;
}

// ---------------- all weight transposes in one dispatch ----------------
// grid (2048+256, 1, 2): fl<2048 -> Wd1 (K=1024,N=2048); else Wd2 (K=2048,N=128)
__global__ void k_transpose_all(const float* __restrict__ Wd1, const float* __restrict__ mWd1,
                                const float* __restrict__ Wd2, const float* __restrict__ mWd2,
                                ushort* __restrict__ Wt1, ushort* __restrict__ Wt2) {
  int fl = blockIdx.x, z = blockIdx.z;
  const float* W;
  ushort* o;
  int bx, by, K, N;
  if (fl < 2048) {
    W = z ? mWd1 : Wd1;
    o = Wt1 + (size_t)z * 2097152;
    bx = fl & 63; by = fl >> 6; K = 1024; N = 2048;
  } else {
    fl -= 2048;
    W = z ? mWd2 : Wd2;
    o = Wt2 + (size_t)z * 262144;
    bx = fl & 3; by = fl >> 2; K = 2048; N = 128;
  }
  __shared__ float tile[32][33];
  int n0 = bx * 32, k0 = by * 32;
  int tx = threadIdx.x & 31, ty = threadIdx.x >> 5;
#pragma unroll
  for (int i = 0; i < 32; i += 8)
    tile[ty + i][tx] = W[(size_t)(k0 + ty + i) * N + n0 + tx];
  __syncthreads();
#pragma unroll
  for (int i = 0; i < 32; i += 8)
    o[(size_t)(n0 + ty + i) * K + k0 + tx] = f2bf(tile[tx][ty + i]);
}

// ============ E1: 128x128 2-phase dbuf GEMM, q+k batched (grid 16,49,2) ============
__global__ __launch_bounds__(256) void k_gemm_e1(
    const ushort* __restrict__ A, long sA, const ushort* __restrict__ B, long sB,
    const float* __restrict__ bias0, const float* __restrict__ bias1,
    ushort* __restrict__ O, long sO, int K, int ldOut) {
  __shared__ unsigned char smem[65536];
  const int tid = threadIdx.x;
  int bx = blockIdx.x, by = blockIdx.y;
  const int bz = blockIdx.z;
  xcd_swizzle(gridDim.x, gridDim.y, bx, by);
  const ushort* Ab = A + (size_t)bz * sA;
  const ushort* Bb = B + (size_t)bz * sB;
  const float* bias = bz ? bias1 : bias0;
  ushort* Ob = O + (size_t)bz * sO;
  const int mBase = by * 128, nBase = bx * 128;
  const int lane = tid & 63;
  const int wid = tid >> 6;
  const int wid_u = __builtin_amdgcn_readfirstlane(wid);
  const int wm = wid >> 1, wn = wid & 1;
  const int lg = lane >> 4, li = lane & 15;
  const int lrow = lane >> 3, lchunk = lane & 7;

  const ushort* aSrc[4];
  const ushort* bSrc[4];
  int ldsOff[4];
#pragma unroll
  for (int j = 0; j < 4; ++j) {
    int r = wid_u * 32 + j * 8 + lrow;
    int gc = (lchunk ^ lrow) << 3;
    aSrc[j] = Ab + (size_t)(mBase + r) * K + gc;
    bSrc[j] = Bb + (size_t)(nBase + r) * K + gc;
    ldsOff[j] = (wid_u * 32 + j * 8) * 128;
  }
  f32x4 acc[4][4] = {};

  auto STAGE = [&](int buf, int k0) {
    unsigned base = (unsigned)buf * 32768u;
#pragma unroll
    for (int j = 0; j < 4; ++j) {
      gload_lds16(aSrc[j] + k0, smem + base + ldsOff[j]);
      gload_lds16(bSrc[j] + k0, smem + base + 16384 + ldsOff[j]);
    }
  };

  const int nt = K >> 6;
  STAGE(0, 0);
  __syncthreads();
  for (int t = 0; t < nt; ++t) {
    if (t + 1 < nt) STAGE((t + 1) & 1, (t + 1) << 6);
    const unsigned char* As = smem + (t & 1) * 32768;
    const unsigned char* Bs = As + 16384;
#pragma unroll
    for (int ks = 0; ks < 2; ++ks) {
      s16x8 af[4], bfr[4];
#pragma unroll
      for (int mi = 0; mi < 4; ++mi) {
        int r = wm * 64 + mi * 16 + li;
        af[mi] = *(const s16x8*)(const void*)(As + r * 128 + ((ks * 64 + lg * 16) ^ ((r & 7) << 4)));
      }
#pragma unroll
      for (int ni = 0; ni < 4; ++ni) {
        int c = wn * 64 + ni * 16 + li;
        bfr[ni] = *(const s16x8*)(const void*)(Bs + c * 128 + ((ks * 64 + lg * 16) ^ ((c & 7) << 4)));
      }
#pragma unroll
      for (int mi = 0; mi < 4; ++mi)
#pragma unroll
        for (int ni = 0; ni < 4; ++ni)
          acc[mi][ni] = __builtin_amdgcn_mfma_f32_16x16x32_bf16(af[mi], bfr[ni], acc[mi][ni], 0, 0, 0);
    }
    __syncthreads();
  }

#pragma unroll
  for (int ni = 0; ni < 4; ++ni) {
    int c = nBase + wn * 64 + ni * 16 + li;
    float bv = bias[c];
#pragma unroll
    for (int mi = 0; mi < 4; ++mi) {
#pragma unroll
      for (int rg = 0; rg < 4; ++rg) {
        int r = mBase + wm * 64 + mi * 16 + lg * 4 + rg;
        float v = fmaxf(acc[mi][ni][rg] + bv, 0.f);
        Ob[(size_t)r * ldOut + c] = f2bf(v);
      }
    }
  }
}

// ============ E2: 128x128 2-phase dbuf GEMM, raw f32 partials ============
// grid (1,49,8): bz = branch*4 + kslice; full tiles (M=6272, N=128)
__global__ __launch_bounds__(256) void k_gemm_e2(
    const ushort* __restrict__ A, const ushort* __restrict__ B, float* __restrict__ o0,
    int Kloop, int lda, int ldb, long sA, long sB) {
  __shared__ unsigned char smem[65536];
  const int tid = threadIdx.x;
  int bx = blockIdx.x, by = blockIdx.y;
  const int bz = blockIdx.z;
  xcd_swizzle(gridDim.x, gridDim.y, bx, by);
  const ushort* Ab = A + (size_t)(bz >> 2) * sA + (size_t)(bz & 3) * Kloop;
  const ushort* Bb = B + (size_t)(bz >> 2) * sB + (size_t)(bz & 3) * Kloop;
  const int mBase = by * 128, nBase = bx * 128;
  const int lane = tid & 63;
  const int wid = tid >> 6;
  const int wid_u = __builtin_amdgcn_readfirstlane(wid);
  const int wm = wid >> 1, wn = wid & 1;
  const int lg = lane >> 4, li = lane & 15;
  const int lrow = lane >> 3, lchunk = lane & 7;

  const ushort* aSrc[4];
  const ushort* bSrc[4];
  int ldsOff[4];
#pragma unroll
  for (int j = 0; j < 4; ++j) {
    int r = wid_u * 32 + j * 8 + lrow;
    int gc = (lchunk ^ lrow) << 3;
    aSrc[j] = Ab + (size_t)(mBase + r) * lda + gc;
    bSrc[j] = Bb + (size_t)(nBase + r) * ldb + gc;
    ldsOff[j] = (wid_u * 32 + j * 8) * 128;
  }
  f32x4 acc[4][4] = {};

  auto STAGE = [&](int buf, int k0) {
    unsigned base = (unsigned)buf * 32768u;
#pragma unroll
    for (int j = 0; j < 4; ++j) {
      gload_lds16(aSrc[j] + k0, smem + base + ldsOff[j]);
      gload_lds16(bSrc[j] + k0, smem + base + 16384 + ldsOff[j]);
    }
  };

  const int nt = Kloop >> 6;
  STAGE(0, 0);
  __syncthreads();
  for (int t = 0; t < nt; ++t) {
    if (t + 1 < nt) STAGE((t + 1) & 1, (t + 1) << 6);
    const unsigned char* As = smem + (t & 1) * 32768;
    const unsigned char* Bs = As + 16384;
#pragma unroll
    for (int ks = 0; ks < 2; ++ks) {
      s16x8 af[4], bfr[4];
#pragma unroll
      for (int mi = 0; mi < 4; ++mi) {
        int r = wm * 64 + mi * 16 + li;
        af[mi] = *(const s16x8*)(const void*)(As + r * 128 + ((ks * 64 + lg * 16) ^ ((r & 7) << 4)));
      }
#pragma unroll
      for (int ni = 0; ni < 4; ++ni) {
        int c = wn * 64 + ni * 16 + li;
        bfr[ni] = *(const s16x8*)(const void*)(Bs + c * 128 + ((ks * 64 + lg * 16) ^ ((c & 7) << 4)));
      }
#pragma unroll
      for (int mi = 0; mi < 4; ++mi)
#pragma unroll
        for (int ni = 0; ni < 4; ++ni)
          acc[mi][ni] = __builtin_amdgcn_mfma_f32_16x16x32_bf16(af[mi], bfr[ni], acc[mi][ni], 0, 0, 0);
    }
    __syncthreads();
  }

#pragma unroll
  for (int ni = 0; ni < 4; ++ni) {
    int c = nBase + wn * 64 + ni * 16 + li;
#pragma unroll
    for (int mi = 0; mi < 4; ++mi)
#pragma unroll
      for (int rg = 0; rg < 4; ++rg) {
        int r = mBase + wm * 64 + mi * 16 + lg * 4 + rg;
        o0[(size_t)bz * 802816 + (size_t)r * 128 + c] = acc[mi][ni][rg];
      }
  }
}

// ============ K=128 GEMM, NO LDS (operands L2-resident): direct global->VGPR frags ====
// EPI 2: per-row sum(exp(acc*scale)) -> psum[row][bx]; EPI 3: per-row (max,argmax)
template <int EPI>
__global__ __launch_bounds__(256) void k_gemm_k128(
    const ushort* __restrict__ A, const ushort* __restrict__ B,
    float* __restrict__ o0, int* __restrict__ o1,
    int Mvalid, int Nvalid, int ntiles, float scale, long sA, long sB) {
  __shared__ unsigned char smem[2048];
  const int tid = threadIdx.x;
  int bx = blockIdx.x, by = blockIdx.y;
  const int bz = blockIdx.z;
  xcd_swizzle(gridDim.x, gridDim.y, bx, by);
  const ushort* Ab = A + (size_t)bz * sA;
  const ushort* Bb = B + (size_t)bz * sB;
  const int mBase = by * 128, nBase = bx * 128;
  const int lane = tid & 63;
  const int wid = tid >> 6;
  const int wm = wid >> 1, wn = wid & 1;
  const int lg = lane >> 4, li = lane & 15;

  // direct fragment loads: per (mi|ni, ks) a 16B load; wave = 16 rows x 64B contiguous
  s16x8 af[4][2], bfr[4][2];
#pragma unroll
  for (int mi = 0; mi < 4; ++mi) {
    int r = mBase + wm * 64 + mi * 16 + li;
    r = r < Mvalid ? r : Mvalid - 1;
#pragma unroll
    for (int ks = 0; ks < 2; ++ks)
      af[mi][ks] = *(const s16x8*)(const void*)(Ab + (size_t)r * 128 + ks * 32 + lg * 8);
  }
#pragma unroll
  for (int ni = 0; ni < 4; ++ni) {
    int c = nBase + wn * 64 + ni * 16 + li;
    c = c < Nvalid ? c : Nvalid - 1;
#pragma unroll
    for (int ks = 0; ks < 2; ++ks)
      bfr[ni][ks] = *(const s16x8*)(const void*)(Bb + (size_t)c * 128 + ks * 32 + lg * 8);
  }
  f32x4 acc[4][4] = {};
#pragma unroll
  for (int ks = 0; ks < 2; ++ks)
#pragma unroll
    for (int mi = 0; mi < 4; ++mi)
#pragma unroll
      for (int ni = 0; ni < 4; ++ni)
        acc[mi][ni] = __builtin_amdgcn_mfma_f32_16x16x32_bf16(af[mi][ks], bfr[ni][ks], acc[mi][ni], 0, 0, 0);

  if constexpr (EPI == 2) {
    float* reds = (float*)(void*)smem;   // [128][2]
#pragma unroll
    for (int mi = 0; mi < 4; ++mi)
#pragma unroll
      for (int rg = 0; rg < 4; ++rg) {
        float s = fexp2(acc[mi][0][rg] * scale) + fexp2(acc[mi][1][rg] * scale) +
                  fexp2(acc[mi][2][rg] * scale) + fexp2(acc[mi][3][rg] * scale);
#pragma unroll
        for (int d = 1; d < 16; d <<= 1) s += __shfl_xor(s, d);
        int rl = wm * 64 + mi * 16 + lg * 4 + rg;
        if (li == 0) reds[rl * 2 + wn] = s;
      }
    __syncthreads();
    if (tid < 128) {
      size_t idx = (size_t)(mBase + tid) * ntiles + bx;
      o0[idx] = reds[tid * 2] + reds[tid * 2 + 1];
    }
  } else {
    float* redv = (float*)(void*)smem;          // [128][2]
    int* redi = (int*)(void*)(smem + 1024);
#pragma unroll
    for (int mi = 0; mi < 4; ++mi)
#pragma unroll
      for (int rg = 0; rg < 4; ++rg) {
        float bv = -3.4e38f;
        int bi = 0x7fffffff;
#pragma unroll
        for (int ni = 0; ni < 4; ++ni) {
          int c = nBase + wn * 64 + ni * 16 + li;
          float v = (c < Nvalid) ? acc[mi][ni][rg] : -3.4e38f;
          if (v > bv || (v == bv && c < bi)) { bv = v; bi = c; }
        }
#pragma unroll
        for (int d = 1; d < 16; d <<= 1) {
          float ov = __shfl_xor(bv, d);
          int oi = __shfl_xor(bi, d);
          if (ov > bv || (ov == bv && oi < bi)) { bv = ov; bi = oi; }
        }
        int rl = wm * 64 + mi * 16 + lg * 4 + rg;
        if (li == 0) { redv[rl * 2 + wn] = bv; redi[rl * 2 + wn] = bi; }
      }
    __syncthreads();
    if (tid < 128) {
      int r = mBase + tid;
      if (r < Mvalid) {
        float v0 = redv[tid * 2], v1 = redv[tid * 2 + 1];
        int i0 = redi[tid * 2], i1 = redi[tid * 2 + 1];
        float v = v0; int bi2 = i0;
        if (v1 > v || (v1 == v && i1 < bi2)) { v = v1; bi2 = i1; }
        size_t idx = (size_t)(bz * Mvalid + r) * ntiles + bx;
        o0[idx] = v;
        o1[idx] = bi2;
      }
    }
  }
}

// ---------------- sum 4 K-slice partials + bias, l2-normalize; q+k batched -----------
__global__ void k_l2n_rows(const float* __restrict__ part, const float* __restrict__ bias0,
                           const float* __restrict__ bias1, float* __restrict__ of,
                           ushort* __restrict__ ob) {
  int br = blockIdx.y;
  const float* p = part + (size_t)br * 3211264;
  const float* bias = br ? bias1 : bias0;
  float* o = of + (size_t)br * 802816;
  ushort* o2 = ob + (size_t)br * 802816;
  int row = blockIdx.x * 4 + (threadIdx.x >> 6);
  int lane = threadIdx.x & 63;
  size_t i0 = (size_t)row * 128 + lane;
  const size_t SL = 802816;
  float v0 = bias[lane]      + p[i0]      + p[SL + i0]      + p[2 * SL + i0]      + p[3 * SL + i0];
  float v1 = bias[lane + 64] + p[i0 + 64] + p[SL + i0 + 64] + p[2 * SL + i0 + 64] + p[3 * SL + i0 + 64];
  float ss = v0 * v0 + v1 * v1;
#pragma unroll
  for (int d = 1; d < 64; d <<= 1) ss += __shfl_xor(ss, d);
  float r = 1.0f / sqrtf(fmaxf(ss, 1e-12f));
  o[i0] = v0 * r;
  o[i0 + 64] = v1 * r;
  o2[i0] = f2bf(v0 * r);
  o2[i0 + 64] = f2bf(v1 * r);
}

// ---------------- argmax finalize + gather ----------------
__global__ void k_argmax_gather(const float* __restrict__ pval, const int* __restrict__ pidx,
                                const ushort* __restrict__ kd_bf, ushort* __restrict__ matched_bf,
                                int* __restrict__ idxf) {
  int n = blockIdx.x;
  int b = n / 784;
  float bv = pval[(size_t)n * 7];
  int bi = pidx[(size_t)n * 7];
#pragma unroll
  for (int t = 1; t < 7; ++t) {
    float v = pval[(size_t)n * 7 + t];
    int i2 = pidx[(size_t)n * 7 + t];
    if (v > bv) { bv = v; bi = i2; }
  }
  int lane = threadIdx.x;
  if (lane == 0) idxf[n] = bi;
  const ushort* src = kd_bf + (size_t)(b * 784 + bi) * 128;
  ushort* dst = matched_bf + (size_t)n * 128;
  dst[lane] = src[lane];
  dst[lane + 64] = src[lane + 64];
}

// ---------------- merged: queue InfoNCE partials (bx<256) + per-row LSE (bx>=256) ----
__global__ __launch_bounds__(256) void k_qrow(const float* __restrict__ queue,
                                              const float* __restrict__ qg,
                                              float* __restrict__ ps,
                                              const float* __restrict__ psum,
                                              const int* __restrict__ idxf,
                                              const float* __restrict__ qd,
                                              const float* __restrict__ kd,
                                              float* __restrict__ diff) {
  __shared__ float qs[1024];
  __shared__ float lssum[8][4];
  int tid = threadIdx.x;
  int lane = tid & 63, w = tid >> 6;
  if (blockIdx.x < 256) {
    for (int i = tid; i < 1024; i += 256) qs[i] = qg[i];
    __syncthreads();
    int r = blockIdx.x * 256 + tid;
    const float* qr = queue + (size_t)r * 128;
    float a[8] = {0, 0, 0, 0, 0, 0, 0, 0};
    for (int j = 0; j < 128; j += 4) {
      float4 v = *(const float4*)(const void*)(qr + j);
#pragma unroll
      for (int b = 0; b < 8; ++b)
        a[b] += v.x * qs[b * 128 + j] + v.y * qs[b * 128 + j + 1] +
                v.z * qs[b * 128 + j + 2] + v.w * qs[b * 128 + j + 3];
    }
#pragma unroll
    for (int b = 0; b < 8; ++b) {
      float s = fexp2(a[b] * (TAU_INV * L2E));
#pragma unroll
      for (int d = 1; d < 64; d <<= 1) s += __shfl_xor(s, d);
      if (lane == 0) lssum[b][w] = s;
    }
    __syncthreads();
    if (tid < 8) {
      int b = tid;
      ps[blockIdx.x * 8 + b] = lssum[b][0] + lssum[b][1] + lssum[b][2] + lssum[b][3];
    }
  } else {
    int n = (blockIdx.x - 256) * 4 + w;
    float s = (lane < 49) ? psum[(size_t)n * 49 + lane] : 0.f;
#pragma unroll
    for (int d = 1; d < 64; d <<= 1) s += __shfl_xor(s, d);
    int b = n / 784;
    int mr = b * 784 + idxf[n];
    float pos = qd[(size_t)n * 128 + lane] * kd[(size_t)mr * 128 + lane] +
                qd[(size_t)n * 128 + 64 + lane] * kd[(size_t)mr * 128 + 64 + lane];
#pragma unroll
    for (int d = 1; d < 64; d <<= 1) pos += __shfl_xor(pos, d);
    if (lane == 0) diff[n] = logf(s) - pos * TAU_INV;
  }
}

// ---------------- final combine (max-free) ----------------
__global__ void k_final(const float* __restrict__ ps, const float* __restrict__ lpos,
                        const float* __restrict__ diff, float* __restrict__ out) {
  int tid = threadIdx.x;
  int lane = tid & 63, w = tid >> 6;
  __shared__ float sm[4];
  float lg = 0.f;
  for (int b = 0; b < 8; ++b) {
    float s = ps[tid * 8 + b];
#pragma unroll
    for (int d = 1; d < 64; d <<= 1) s += __shfl_xor(s, d);
    if (lane == 0) sm[w] = s;
    __syncthreads();
    if (tid == 0) {
      float S = sm[0] + sm[1] + sm[2] + sm[3];
      float lp = lpos[b] * TAU_INV;
      S += fexp2(lp * L2E);
      lg += logf(S) - lp;
    }
    __syncthreads();
  }
  float v = 0.f;
  for (int i = tid; i < 6272; i += 256) v += diff[i];
#pragma unroll
  for (int d = 1; d < 64; d <<= 1) v += __shfl_xor(v, d);
  if (lane == 0) sm[w] = v;
  __syncthreads();
  if (tid == 0) {
    float ld = sm[0] + sm[1] + sm[2] + sm[3];
    out[0] = 0.5f * (lg * 0.125f) + 0.5f * (ld * (1.0f / 6272.0f));
  }
}

extern "C" void kernel_launch(void* const* d_in, const int* in_sizes, int n_in,
                              void* d_out, int out_size, void* d_ws, size_t ws_size,
                              hipStream_t stream) {
  (void)in_sizes; (void)n_in; (void)out_size; (void)ws_size;
  const float* feat_q = (const float*)d_in[0];
  const float* feat_k = (const float*)d_in[1];
  const float* Wg1 = (const float*)d_in[2];
  const float* bg1 = (const float*)d_in[3];
  const float* Wg2 = (const float*)d_in[4];
  const float* bg2 = (const float*)d_in[5];
  const float* Wd1 = (const float*)d_in[6];
  const float* bd1 = (const float*)d_in[7];
  const float* Wd2 = (const float*)d_in[8];
  const float* bd2 = (const float*)d_in[9];
  const float* mWg1 = (const float*)d_in[10];
  const float* mbg1 = (const float*)d_in[11];
  const float* mWg2 = (const float*)d_in[12];
  const float* mbg2 = (const float*)d_in[13];
  const float* mWd1 = (const float*)d_in[14];
  const float* mbd1 = (const float*)d_in[15];
  const float* mWd2 = (const float*)d_in[16];
  const float* mbd2 = (const float*)d_in[17];
  const float* queue = (const float*)d_in[18];
  float* out = (float*)d_out;

  char* ws = (char*)d_ws;
  size_t off = 0;
  auto alloc = [&](size_t bytes) -> void* {
    void* p = (void*)(ws + off);
    off += (bytes + 255) & ~(size_t)255;
    return p;
  };

  // joint (q,k) buffers; branch element-strides in comments
  ushort* feat_bf = (ushort*)alloc(2ull * 6272 * 1024 * 2);   // +6422528
  ushort* Wd1t2 = (ushort*)alloc(2ull * 2048 * 1024 * 2);     // +2097152
  ushort* Wd2t2 = (ushort*)alloc(2ull * 128 * 2048 * 2);      // +262144
  ushort* h_bf2 = (ushort*)alloc(2ull * 6272 * 2048 * 2);     // +12845056
  float* e2part2 = (float*)alloc(2ull * 4 * 6272 * 128 * 4);  // +3211264
  float* qdkd = (float*)alloc(2ull * 6272 * 128 * 4);         // +802816
  ushort* qdkd_bf = (ushort*)alloc(2ull * 6272 * 128 * 2);    // +802816
  ushort* matched_bf = (ushort*)alloc(6272ull * 128 * 2);
  float* psum = (float*)alloc(6272ull * 49 * 4);
  float* pval = (float*)alloc(6272ull * 7 * 4);
  int* pidx = (int*)alloc(6272ull * 7 * 4);
  int* idxf = (int*)alloc(6272ull * 4);
  float* gpart = (float*)alloc(16ull * 112 * 1024 * 4);
  float* g2 = (float*)alloc(2ull * 8 * 1024 * 4);             // +8192
  float* part1 = (float*)alloc(2ull * 16 * 8 * 2048 * 4);     // +262144
  float* part2 = (float*)alloc(2ull * 32 * 8 * 128 * 4);      // +32768
  float* qg = (float*)alloc(8ull * 128 * 4);
  float* kg = (float*)alloc(8ull * 128 * 4);
  float* l_pos = (float*)alloc(8ull * 4);
  float* qpart_s = (float*)alloc(256ull * 8 * 4);
  float* diff = (float*)alloc(6272ull * 4);

  k_cvt_pool<<<dim3(112, 16), 256, 0, stream>>>(feat_q, feat_k, feat_bf, gpart);
  k_gpool_fin<<<64, 256, 0, stream>>>(gpart, g2);

  k_transpose_all<<<dim3(2304, 1, 2), 256, 0, stream>>>(Wd1, mWd1, Wd2, mWd2, Wd1t2, Wd2t2);

  k_dense1_part<<<dim3(8, 16, 2), 256, 0, stream>>>(g2, Wg1, mWg1, part1);
  k_d12<<<dim3(32, 2), 128, 0, stream>>>(part1, bg1, mbg1, Wg2, mWg2, part2);
  k_head_fin<<<8, 64, 0, stream>>>(part2, part2 + 32768, bg2, mbg2, qg, kg, l_pos);

  // E1 batched: h = relu(feat @ Wd1 + b)
  k_gemm_e1<<<dim3(16, 49, 2), 256, 0, stream>>>(feat_bf, 6422528, Wd1t2, 2097152,
                                                 bd1, mbd1, h_bf2, 12845056, 1024, 2048);
  // E2 batched (branch x 4 K-slices)
  k_gemm_e2<<<dim3(1, 49, 8), 256, 0, stream>>>(h_bf2, Wd2t2, e2part2,
                                                512, 2048, 2048, 12845056, 262144);
  k_l2n_rows<<<dim3(1568, 2), 256, 0, stream>>>(e2part2, bd2, mbd2, qdkd, qdkd_bf);

  // dense correspondence (K=128, no-LDS)
  k_gemm_k128<3><<<dim3(7, 7, 8), 256, 0, stream>>>(qdkd_bf, qdkd_bf + 802816, pval, pidx,
                                                    784, 784, 7, 0.f, 784l * 128, 784l * 128);
  k_argmax_gather<<<6272, 64, 0, stream>>>(pval, pidx, qdkd_bf + 802816, matched_bf, idxf);

  // dense InfoNCE partials (K=128, no-LDS, max-free)
  k_gemm_k128<2><<<dim3(49, 49, 1), 256, 0, stream>>>(qdkd_bf, matched_bf, psum, nullptr,
                                                      6272, 6272, 49, TAU_INV * L2E, 0, 0);

  // queue InfoNCE + per-row LSE (merged)
  k_qrow<<<1824, 256, 0, stream>>>(queue, qg, qpart_s, psum, idxf, qdkd, qdkd + 802816, diff);
  k_final<<<1, 256, 0, stream>>>(qpart_s, l_pos, diff, out);
}